// Round 11
// baseline (270.667 us; speedup 1.0000x reference)
//
#include <hip/hip_runtime.h>
#include <math.h>

#define B_ 2
#define C_ 64
#define H_ 192
#define W_ 192
#define HW_ (H_*W_)
#define PR_ 194      // padded row length (W+2)

typedef __attribute__((ext_vector_type(8))) short    bf16x8;
typedef __attribute__((ext_vector_type(4))) float    f32x4;
typedef __attribute__((ext_vector_type(4))) unsigned u32x4;

__device__ inline unsigned short f2bf(float f) {           // RNE fp32->bf16
  unsigned u = __float_as_uint(f);
  return (unsigned short)((u + 0x7fffu + ((u >> 16) & 1u)) >> 16);
}
__device__ inline float bf2f(unsigned short h) { return __uint_as_float((unsigned)h << 16); }
__device__ inline float bflo(unsigned u) { return __uint_as_float(u << 16); }
__device__ inline float bfhi(unsigned u) { return __uint_as_float(u & 0xffff0000u); }
__device__ inline unsigned pkbf(float a, float b) {
  unsigned ua = __float_as_uint(a), ub = __float_as_uint(b);
  ua = (ua + 0x7fffu + ((ua >> 16) & 1u)) >> 16;
  ub = (ub + 0x7fffu + ((ub >> 16) & 1u)) >> 16;
  return ua | (ub << 16);
}

// ---------------------------------------------------------------------------
// conv weight OIHW fp32 -> 16x16-FRAGMENT-MAJOR hi/lo bf16 (round-8 layout):
// WF[k][o/16][c/32][l16=o%16][g=(c%32)/8][8ch] — each MFMA A-fragment is one
// contiguous 1KB block (lane reads base + (l16*4+g)*16B, fully coalesced).
// ---------------------------------------------------------------------------
template<int O, int CIN, int OPAD, int CPAD>
__global__ __launch_bounds__(256) void prep_cw(const float* __restrict__ w,
                                               unsigned short* __restrict__ WH,
                                               unsigned short* __restrict__ WL)
{
  const int i = blockIdx.x * 256 + threadIdx.x;
  if (i >= 9 * OPAD * CPAD) return;
  const int k = i / (OPAD * CPAD);
  const int r = i % (OPAD * CPAD);
  const int o = r / CPAD;
  const int c = r % CPAD;
  float v = (o < O && c < CIN) ? w[((size_t)o * CIN + c) * 9 + k] : 0.f;
  const unsigned short h = f2bf(v);
  const int ot = o >> 4, l16 = o & 15;
  const int cc = c >> 5, g = (c >> 3) & 3, e = c & 7;
  const size_t off = (((((size_t)k * (OPAD / 16) + ot) * (CPAD / 32) + cc) * 16 + l16) * 4 + g) * 8 + e;
  WH[off] = h;
  WL[off] = f2bf(v - bf2f(h));
}

// ---------------------------------------------------------------------------
// cond_feat fp32 NCHW (131ch) -> chunked padded NHWC-32 hi/lo bf16:
// layout [b][cc(5)][194][194][32]. One block per (b, padded row, cc-chunk).
// ---------------------------------------------------------------------------
__global__ __launch_bounds__(256) void transpose_cond(const float* __restrict__ cond,
                                                      unsigned short* __restrict__ cH,
                                                      unsigned short* __restrict__ cL)
{
  const int tid = threadIdx.x;
  const int b  = blockIdx.x / PR_;
  const int yp = blockIdx.x % PR_;
  const int cc = blockIdx.y;
  const size_t ob = (((size_t)(b * 5 + cc) * PR_ + yp) * PR_) * 32;

  if (yp == 0 || yp == PR_ - 1) {                 // halo row: all zeros
    u32x4 z = {0, 0, 0, 0};
    for (int idx = tid; idx < PR_ * 4; idx += 256) {
      *(u32x4*)(cH + ob + (size_t)idx * 8) = z;
      *(u32x4*)(cL + ob + (size_t)idx * 8) = z;
    }
    return;
  }
  const int y = yp - 1;
  __shared__ float t[32][PR_];

  for (int idx = tid; idx < 32 * 192; idx += 256) {
    const int ci = idx / 192, px = idx % 192;
    const int c = cc * 32 + ci;
    t[ci][px + 1] = (c < 131) ? cond[(((size_t)b * 131 + c) * H_ + y) * W_ + px] : 0.f;
  }
  if (tid < 32) { t[tid][0] = 0.f; t[tid][PR_ - 1] = 0.f; }
  __syncthreads();
  for (int idx = tid; idx < PR_ * 4; idx += 256) {   // (px, 8ch-seg)
    const int px = idx >> 2, sg = idx & 3;
    u32x4 vh, vl;
    #pragma unroll
    for (int q = 0; q < 4; ++q) {
      const int c0 = sg * 8 + q * 2;
      const float va = t[c0][px], vb = t[c0 + 1][px];
      const unsigned short ha = f2bf(va), hb = f2bf(vb);
      vh[q] = (unsigned)ha | ((unsigned)hb << 16);
      const unsigned short la = f2bf(va - bf2f(ha)), lb = f2bf(vb - bf2f(hb));
      vl[q] = (unsigned)la | ((unsigned)lb << 16);
    }
    *(u32x4*)(cH + ob + (size_t)idx * 8) = vh;
    *(u32x4*)(cL + ob + (size_t)idx * 8) = vl;
  }
}

// ---------------------------------------------------------------------------
// zero halo of chunked padded NHWC-32 hi/lo pair ([b][2][194][194][32])
// ---------------------------------------------------------------------------
__global__ __launch_bounds__(256) void halo_zero(unsigned short* __restrict__ H,
                                                 unsigned short* __restrict__ L)
{
  const int idx = blockIdx.x * 256 + threadIdx.x;
  if (idx >= B_ * 2 * PR_ * PR_) return;
  const int r  = idx % (PR_ * PR_);
  const int yp = r / PR_, xp = r % PR_;
  if (yp == 0 || yp == PR_ - 1 || xp == 0 || xp == PR_ - 1) {
    u32x4 z = {0, 0, 0, 0};
    const size_t base = (size_t)idx * 32;
    #pragma unroll
    for (int j = 0; j < 4; ++j) {
      *(u32x4*)(H + base + j * 8) = z;
      *(u32x4*)(L + base + j * 8) = z;
    }
  }
}

// ---------------------------------------------------------------------------
// MFMA 3x3 conv (round-8 oc-strip structure). Tile 64px x (NW*16) oc.
// HI plane staged in LDS (swizzled); LO plane B-fragments read DIRECTLY from
// global (coalesced 1KB spans, L1/L2-served) -> LDS-pipe instructions ~halved,
// traffic balanced across LDS and TA pipes. A fragment-major from global.
// 3-term hi/lo MFMA: W_h*x_h + W_l*x_h + W_h*x_l (fp32 acc).
// EPI 0: lrelu -> hi/lo split -> chunked padded store. EPI 1: conv4 epilogue.
// ---------------------------------------------------------------------------
template<int NCC, int NW, int EPI>
__global__ __launch_bounds__(NW * 64) void conv_mfma(
    const unsigned short* __restrict__ inH, const unsigned short* __restrict__ inL,
    const unsigned short* __restrict__ WH, const unsigned short* __restrict__ WL,
    const float* __restrict__ bias, const float* __restrict__ flow,
    unsigned short* __restrict__ outH, unsigned short* __restrict__ outL,
    float* __restrict__ om)
{
  constexpr int OPAD = NW * 16;
  const int tid = threadIdx.x;
  const int lane = tid & 63, wv = tid >> 6;
  const int g = lane >> 4, l16 = lane & 15;
  // XCD-chunked bijective remap (1152 blocks, 1152 % 8 == 0)
  const int nwg8 = (3 * 192 * B_) / 8;
  const int t = blockIdx.x;
  const int gi = (t & 7) * nwg8 + (t >> 3);
  const int p0 = (gi % 3) * 64;
  const int y  = (gi / 3) % 192;
  const int b  = gi / 576;

  // smem: staging 3 rows x 264 x 8 shorts (hi only, 12.7KB) / epilogue 18.4KB
  __shared__ __align__(16) unsigned short smem[2 * 64 * 72];   // 9216 shorts

  f32x4 acc[4];
  {
    float bv[4];
    #pragma unroll
    for (int r = 0; r < 4; ++r) {
      const int oc = wv * 16 + g * 4 + r;
      bv[r] = (EPI == 1 && oc >= 27) ? 0.f : bias[oc];
    }
    #pragma unroll
    for (int n = 0; n < 4; ++n) {
      acc[n][0] = bv[0]; acc[n][1] = bv[1]; acc[n][2] = bv[2]; acc[n][3] = bv[3];
    }
  }

  const int fr = l16 * 4 + g;   // fragment-lane index (contiguous 16B slots)

  for (int cc = 0; cc < NCC; ++cc) {
    __syncthreads();
    // stage 3 rows x 66px x 32c HI only, swizzled: slot s holds cg = s ^ ((px>>1)&3)
    for (int ch = tid; ch < 792; ch += NW * 64) {
      const int row = ch / 264, c2 = ch % 264;
      const int px = c2 >> 2, s = c2 & 3;
      const int cg = s ^ ((px >> 1) & 3);
      const size_t so = ((((size_t)b * NCC + cc) * PR_ + (y + row)) * PR_ + p0 + px) * 32 + cg * 8;
      *(u32x4*)(smem + row * 2112 + c2 * 8) = *(const u32x4*)(inH + so);
    }
    __syncthreads();
    #pragma unroll
    for (int ky = 0; ky < 3; ++ky) {
      const unsigned short* stH = smem + ky * 2112;
      const size_t rowBase = ((((size_t)b * NCC + cc) * PR_ + (y + ky)) * PR_ + p0) * 32;
      #pragma unroll
      for (int kx = 0; kx < 3; ++kx) {
        const int k = ky * 3 + kx;
        // fragment-major A: contiguous 1KB block per (k, wv, cc)
        const size_t wo = ((((size_t)k * NW + wv) * NCC + cc) * 64 + fr) * 8;
        const bf16x8 aH = *(const bf16x8*)(WH + wo);
        const bf16x8 aL = *(const bf16x8*)(WL + wo);
        #pragma unroll
        for (int n = 0; n < 4; ++n) {
          const int pxt = n * 16 + l16 + kx;
          // hi from LDS (swizzled), lo directly from global (coalesced 1KB span)
          const int bo = pxt * 32 + ((g ^ ((pxt >> 1) & 3)) * 8);
          const bf16x8 bH = *(const bf16x8*)(stH + bo);
          const bf16x8 bL = *(const bf16x8*)(inL + rowBase + (size_t)pxt * 32 + g * 8);
          acc[n] = __builtin_amdgcn_mfma_f32_16x16x32_bf16(aH, bH, acc[n], 0, 0, 0);
          acc[n] = __builtin_amdgcn_mfma_f32_16x16x32_bf16(aL, bH, acc[n], 0, 0, 0);
          acc[n] = __builtin_amdgcn_mfma_f32_16x16x32_bf16(aH, bL, acc[n], 0, 0, 0);
        }
      }
    }
  }

  if (EPI == 0) {
    // lrelu -> hi/lo split -> LDS transpose -> coalesced chunked store
    __syncthreads();
    unsigned short* eH = smem;
    unsigned short* eL = smem + 64 * 72;
    #pragma unroll
    for (int n = 0; n < 4; ++n) {
      const int px = n * 16 + l16;
      #pragma unroll
      for (int r = 0; r < 4; ++r) {
        const int c = wv * 16 + g * 4 + r;
        float v = acc[n][r];
        v = (v >= 0.f) ? v : 0.1f * v;
        const unsigned short h = f2bf(v);
        eH[px * 72 + c] = h;
        eL[px * 72 + c] = f2bf(v - bf2f(h));
      }
    }
    __syncthreads();
    const int px = tid >> 2, cq = tid & 3;
    const int cc2 = cq >> 1;
    const size_t ob = ((((size_t)b * 2 + cc2) * PR_ + (y + 1)) * PR_ + (p0 + px + 1)) * 32
                    + (cq & 1) * 16;
    *(u32x4*)(outH + ob)     = *(const u32x4*)(eH + px * 72 + cq * 16);
    *(u32x4*)(outH + ob + 8) = *(const u32x4*)(eH + px * 72 + cq * 16 + 8);
    *(u32x4*)(outL + ob)     = *(const u32x4*)(eL + px * 72 + cq * 16);
    *(u32x4*)(outL + ob + 8) = *(const u32x4*)(eL + px * 72 + cq * 16 + 8);
  } else {
    // conv4: offsets (10*tanh + flow_yx) / sigmoid mask -> fp32 NCHW om
    #pragma unroll
    for (int n = 0; n < 4; ++n) {
      const int px = p0 + n * 16 + l16;
      #pragma unroll
      for (int r = 0; r < 4; ++r) {
        const int oc = wv * 16 + g * 4 + r;
        if (oc >= 27) continue;
        float v = acc[n][r];
        if (oc < 18) {
          const float f = flow[(((size_t)b * 2 + ((oc & 1) ? 0 : 1)) * H_ + y) * W_ + px];
          v = 10.f * tanhf(v) + f;
        } else {
          v = 1.f / (1.f + expf(-v));
        }
        om[((size_t)(b * 27 + oc) * HW_) + (size_t)y * W_ + px] = v;
      }
    }
  }
}

// ---------------------------------------------------------------------------
// deform weight (O=64,C=64,3,3) fp32 -> FRAGMENT-MAJOR bf16:
// W2F[k][o/16][c/32][l16][g][8] — contiguous 1KB per A-fragment.
// ---------------------------------------------------------------------------
__global__ __launch_bounds__(256) void prep_w2(const float* __restrict__ w,
                                               unsigned short* __restrict__ W2)
{
  const int i = blockIdx.x * 256 + threadIdx.x;
  if (i < 64 * 64 * 9) {
    const int o = i / 576;
    const int rem = i % 576;
    const int c = rem / 9;
    const int k = rem % 9;
    const int wv = o >> 4, l16 = o & 15;
    const int half = c >> 5, g = (c >> 3) & 3, e = c & 7;
    const size_t off = (((((size_t)k * 4 + wv) * 2 + half) * 16 + l16) * 4 + g) * 8 + e;
    W2[off] = f2bf(w[i]);
  }
}

// ---------------------------------------------------------------------------
// x NCHW fp32 -> NHWC bf16: xTb[b][p][c]
// ---------------------------------------------------------------------------
__global__ __launch_bounds__(256) void transpose_x(const float* __restrict__ x,
                                                   unsigned short* __restrict__ xTb)
{
  const int tid = threadIdx.x;
  const int lane = tid & 63, wv = tid >> 6;
  const int blocksPerB = HW_ / 64;
  const int b = blockIdx.x / blocksPerB;
  const int p0 = (blockIdx.x % blocksPerB) * 64;

  __shared__ float t[64][65];
  const float* xb = x + (size_t)b * C_ * HW_;
  #pragma unroll
  for (int j = 0; j < 16; ++j) {
    const int c = wv * 16 + j;
    t[c][lane] = xb[(size_t)c * HW_ + p0 + lane];
  }
  __syncthreads();
  unsigned short* xo = xTb + ((size_t)b * HW_ + p0) * 64;
  const int c4 = (tid & 15) * 4;
  const int pb = tid >> 4;
  #pragma unroll
  for (int pp = 0; pp < 4; ++pp) {
    const int p = pb + 16 * pp;
    ushort4 v = { f2bf(t[c4][p]), f2bf(t[c4+1][p]), f2bf(t[c4+2][p]), f2bf(t[c4+3][p]) };
    *(ushort4*)(xo + (size_t)p * 64 + c4) = v;
  }
}

// ---------------------------------------------------------------------------
// Deformable conv, bf16 MFMA (round-8 version, verified — unchanged)
// ---------------------------------------------------------------------------
__global__ __launch_bounds__(256) void deform_k(
    const unsigned short* __restrict__ xTb, const float* __restrict__ om,
    const unsigned short* __restrict__ W2, const float* __restrict__ bias,
    float* __restrict__ out)
{
  const int tid = threadIdx.x;
  const int lane = tid & 63, wv = tid >> 6;
  const int g = lane >> 4;
  const int l16 = lane & 15;
  const int blocksPerB = HW_ / 64;
  const int b = blockIdx.x / blocksPerB;
  const int rem = blockIdx.x % blocksPerB;
  const int h = (rem * 64) / W_;
  const int w0 = (rem * 64) % W_;

  __shared__ int   ci[4][9][64];
  __shared__ float cw[4][9][64];
  __shared__ __align__(16) unsigned short valk[64 * 64];

  for (int idx = tid; idx < 9 * 64; idx += 256) {
    const int k = idx >> 6, p = idx & 63;
    const size_t base = (size_t)b * 27 * HW_ + (size_t)h * W_ + w0 + p;
    const float dy = om[base + (size_t)(2 * k) * HW_];
    const float dx = om[base + (size_t)(2 * k + 1) * HW_];
    const float m  = om[base + (size_t)(18 + k) * HW_];
    const int ky = k / 3, kx = k - ky * 3;
    const float py = dy + (float)(h - 1 + ky);
    const float px = dx + (float)(w0 + p - 1 + kx);
    const float y0f = floorf(py), x0f = floorf(px);
    const float ly = py - y0f, lx = px - x0f;
    const int y0 = (int)y0f, x0 = (int)x0f;
    const int y1 = y0 + 1, x1 = x0 + 1;
    float w00 = (1.f - ly) * (1.f - lx), w01 = (1.f - ly) * lx;
    float w10 = ly * (1.f - lx),        w11 = ly * lx;
    if (!(y0 >= 0 && y0 < H_)) { w00 = 0.f; w01 = 0.f; }
    if (!(y1 >= 0 && y1 < H_)) { w10 = 0.f; w11 = 0.f; }
    if (!(x0 >= 0 && x0 < W_)) { w00 = 0.f; w10 = 0.f; }
    if (!(x1 >= 0 && x1 < W_)) { w01 = 0.f; w11 = 0.f; }
    const int yc0 = min(max(y0, 0), H_ - 1), yc1 = min(max(y1, 0), H_ - 1);
    const int xc0 = min(max(x0, 0), W_ - 1), xc1 = min(max(x1, 0), W_ - 1);
    ci[0][k][p] = yc0 * W_ + xc0;  cw[0][k][p] = m * w00;
    ci[1][k][p] = yc0 * W_ + xc1;  cw[1][k][p] = m * w01;
    ci[2][k][p] = yc1 * W_ + xc0;  cw[2][k][p] = m * w10;
    ci[3][k][p] = yc1 * W_ + xc1;  cw[3][k][p] = m * w11;
  }

  f32x4 acc[4];
  {
    float br[4];
    #pragma unroll
    for (int r = 0; r < 4; ++r) br[r] = bias[wv * 16 + g * 4 + r];
    #pragma unroll
    for (int n = 0; n < 4; ++n) { acc[n][0]=br[0]; acc[n][1]=br[1]; acc[n][2]=br[2]; acc[n][3]=br[3]; }
  }

  const unsigned short* xb = xTb + (size_t)b * HW_ * 64;
  const int fr = l16 * 4 + g;
  __syncthreads();

  for (int k = 0; k < 9; ++k) {
    #pragma unroll
    for (int i = 0; i < 2; ++i) {
      const int it = tid + (i << 8);
      const int cg = it & 7, p = it >> 3;
      const int i00 = ci[0][k][p], i01 = ci[1][k][p];
      const int i10 = ci[2][k][p], i11 = ci[3][k][p];
      const float q00 = cw[0][k][p], q01 = cw[1][k][p];
      const float q10 = cw[2][k][p], q11 = cw[3][k][p];
      const u32x4 va = *(const u32x4*)(xb + ((size_t)i00 * 64 + cg * 8));
      const u32x4 vb = *(const u32x4*)(xb + ((size_t)i01 * 64 + cg * 8));
      const u32x4 vc = *(const u32x4*)(xb + ((size_t)i10 * 64 + cg * 8));
      const u32x4 vd = *(const u32x4*)(xb + ((size_t)i11 * 64 + cg * 8));
      u32x4 res;
      #pragma unroll
      for (int j = 0; j < 4; ++j) {
        const float lo = q00*bflo(va[j]) + q01*bflo(vb[j]) + q10*bflo(vc[j]) + q11*bflo(vd[j]);
        const float hi = q00*bfhi(va[j]) + q01*bfhi(vb[j]) + q10*bfhi(vc[j]) + q11*bfhi(vd[j]);
        res[j] = pkbf(lo, hi);
      }
      *(u32x4*)&valk[(p << 6) + ((cg ^ (p & 7)) << 3)] = res;
    }

    const size_t wb = ((((size_t)k * 4 + wv) * 2) * 64 + fr) * 8;
    const bf16x8 a0 = *(const bf16x8*)(W2 + wb);
    const bf16x8 a1 = *(const bf16x8*)(W2 + wb + 512);

    __syncthreads();

    #pragma unroll
    for (int n = 0; n < 4; ++n) {
      const int p = n * 16 + l16;
      const bf16x8 b0 = *(const bf16x8*)&valk[(p << 6) + (((g    ) ^ (p & 7)) << 3)];
      const bf16x8 b1 = *(const bf16x8*)&valk[(p << 6) + (((g + 4) ^ (p & 7)) << 3)];
      acc[n] = __builtin_amdgcn_mfma_f32_16x16x32_bf16(a0, b0, acc[n], 0, 0, 0);
      acc[n] = __builtin_amdgcn_mfma_f32_16x16x32_bf16(a1, b1, acc[n], 0, 0, 0);
    }
    __syncthreads();
  }

  #pragma unroll
  for (int n = 0; n < 4; ++n) {
    #pragma unroll
    for (int r = 0; r < 4; ++r) {
      const int oc = wv * 16 + g * 4 + r;
      out[((size_t)(b * C_ + oc) * HW_) + (size_t)h * W_ + w0 + n * 16 + l16] = acc[n][r];
    }
  }
}

// ---------------------------------------------------------------------------
extern "C" void kernel_launch(void* const* d_in, const int* in_sizes, int n_in,
                              void* d_out, int out_size, void* d_ws, size_t ws_size,
                              hipStream_t stream) {
  const float* x         = (const float*)d_in[0];
  const float* cond_feat = (const float*)d_in[1];
  const float* flow      = (const float*)d_in[2];
  const float* w1 = (const float*)d_in[3];  const float* b1 = (const float*)d_in[4];
  const float* w2 = (const float*)d_in[5];  const float* b2 = (const float*)d_in[6];
  const float* w3 = (const float*)d_in[7];  const float* b3 = (const float*)d_in[8];
  const float* w4 = (const float*)d_in[9];  const float* b4 = (const float*)d_in[10];
  const float* wgt = (const float*)d_in[11]; const float* bias = (const float*)d_in[12];

  float* outp = (float*)d_out;

  // workspace layout (256B-aligned chunks)
  char* wsp = (char*)d_ws;
  size_t off = 0;
  auto alloc = [&](size_t bytes) { char* p = wsp + off; off += (bytes + 255) & ~(size_t)255; return p; };
  const size_t padHW = (size_t)PR_ * PR_;                       // 37636
  unsigned short* condH = (unsigned short*)alloc(B_ * 5 * padHW * 32 * 2);
  unsigned short* condL = (unsigned short*)alloc(B_ * 5 * padHW * 32 * 2);
  unsigned short* hA_H  = (unsigned short*)alloc(B_ * 2 * padHW * 32 * 2);
  unsigned short* hA_L  = (unsigned short*)alloc(B_ * 2 * padHW * 32 * 2);
  unsigned short* hB_H  = (unsigned short*)alloc(B_ * 2 * padHW * 32 * 2);
  unsigned short* hB_L  = (unsigned short*)alloc(B_ * 2 * padHW * 32 * 2);
  float*          om    = (float*)alloc((size_t)B_ * 27 * HW_ * 4);
  unsigned short* xTb   = (unsigned short*)alloc((size_t)B_ * HW_ * 64 * 2);
  unsigned short* W2d   = (unsigned short*)alloc(9 * 64 * 64 * 2);
  unsigned short* W1H   = (unsigned short*)alloc(9 * 64 * 160 * 2);
  unsigned short* W1L   = (unsigned short*)alloc(9 * 64 * 160 * 2);
  unsigned short* W2H   = (unsigned short*)alloc(9 * 64 * 64 * 2);
  unsigned short* W2L   = (unsigned short*)alloc(9 * 64 * 64 * 2);
  unsigned short* W3H   = (unsigned short*)alloc(9 * 64 * 64 * 2);
  unsigned short* W3L   = (unsigned short*)alloc(9 * 64 * 64 * 2);
  unsigned short* W4H   = (unsigned short*)alloc(9 * 32 * 64 * 2);
  unsigned short* W4L   = (unsigned short*)alloc(9 * 32 * 64 * 2);

  // weight prep (16x16 fragment-major)
  prep_cw<64, 131, 64, 160><<<(9*64*160 + 255)/256, 256, 0, stream>>>(w1, W1H, W1L);
  prep_cw<64, 64, 64, 64><<<(9*64*64 + 255)/256, 256, 0, stream>>>(w2, W2H, W2L);
  prep_cw<64, 64, 64, 64><<<(9*64*64 + 255)/256, 256, 0, stream>>>(w3, W3H, W3L);
  prep_cw<27, 64, 32, 64><<<(9*32*64 + 255)/256, 256, 0, stream>>>(w4, W4H, W4L);
  prep_w2<<<144, 256, 0, stream>>>(wgt, W2d);

  // input prep
  transpose_cond<<<dim3(B_ * PR_, 5), 256, 0, stream>>>(cond_feat, condH, condL);
  halo_zero<<<(B_ * 2 * PR_ * PR_ + 255)/256, 256, 0, stream>>>(hA_H, hA_L);
  halo_zero<<<(B_ * 2 * PR_ * PR_ + 255)/256, 256, 0, stream>>>(hB_H, hB_L);
  transpose_x<<<(B_ * HW_)/64, 256, 0, stream>>>(x, xTb);

  // conv chain (MFMA), 1D grid with in-kernel XCD-chunked remap
  const int nwg = 3 * 192 * B_;   // 1152
  conv_mfma<5, 4, 0><<<nwg, 256, 0, stream>>>(condH, condL, W1H, W1L, b1, nullptr, hA_H, hA_L, nullptr);
  conv_mfma<2, 4, 0><<<nwg, 256, 0, stream>>>(hA_H, hA_L, W2H, W2L, b2, nullptr, hB_H, hB_L, nullptr);
  conv_mfma<2, 4, 0><<<nwg, 256, 0, stream>>>(hB_H, hB_L, W3H, W3L, b3, nullptr, hA_H, hA_L, nullptr);
  conv_mfma<2, 2, 1><<<nwg, 128, 0, stream>>>(hA_H, hA_L, W4H, W4L, b4, flow, nullptr, nullptr, om);

  // deformable conv
  deform_k<<<(B_ * HW_)/64, 256, 0, stream>>>(xTb, om, W2d, bias, outp);
}

// Round 12
// 208.135 us; speedup vs baseline: 1.3004x; 1.3004x over previous
//
#include <hip/hip_runtime.h>
#include <math.h>

#define B_ 2
#define C_ 64
#define H_ 192
#define W_ 192
#define HW_ (H_*W_)
#define PR_ 194      // padded row length (W+2)

typedef __attribute__((ext_vector_type(8))) short    bf16x8;
typedef __attribute__((ext_vector_type(4))) float    f32x4;
typedef __attribute__((ext_vector_type(4))) unsigned u32x4;

__device__ inline unsigned short f2bf(float f) {           // RNE fp32->bf16
  unsigned u = __float_as_uint(f);
  return (unsigned short)((u + 0x7fffu + ((u >> 16) & 1u)) >> 16);
}
__device__ inline float bf2f(unsigned short h) { return __uint_as_float((unsigned)h << 16); }
__device__ inline float bflo(unsigned u) { return __uint_as_float(u << 16); }
__device__ inline float bfhi(unsigned u) { return __uint_as_float(u & 0xffff0000u); }
__device__ inline unsigned pkbf(float a, float b) {
  unsigned ua = __float_as_uint(a), ub = __float_as_uint(b);
  ua = (ua + 0x7fffu + ((ua >> 16) & 1u)) >> 16;
  ub = (ub + 0x7fffu + ((ub >> 16) & 1u)) >> 16;
  return ua | (ub << 16);
}

// ---------------------------------------------------------------------------
// conv weight OIHW fp32 -> 16x16-FRAGMENT-MAJOR hi/lo bf16 (round-8 layout):
// WF[k][o/16][c/32][l16=o%16][g=(c%32)/8][8ch] — each MFMA A-fragment is one
// contiguous 1KB block (lane reads base + (l16*4+g)*16B, fully coalesced).
// ---------------------------------------------------------------------------
template<int O, int CIN, int OPAD, int CPAD>
__global__ __launch_bounds__(256) void prep_cw(const float* __restrict__ w,
                                               unsigned short* __restrict__ WH,
                                               unsigned short* __restrict__ WL)
{
  const int i = blockIdx.x * 256 + threadIdx.x;
  if (i >= 9 * OPAD * CPAD) return;
  const int k = i / (OPAD * CPAD);
  const int r = i % (OPAD * CPAD);
  const int o = r / CPAD;
  const int c = r % CPAD;
  float v = (o < O && c < CIN) ? w[((size_t)o * CIN + c) * 9 + k] : 0.f;
  const unsigned short h = f2bf(v);
  const int ot = o >> 4, l16 = o & 15;
  const int cc = c >> 5, g = (c >> 3) & 3, e = c & 7;
  const size_t off = (((((size_t)k * (OPAD / 16) + ot) * (CPAD / 32) + cc) * 16 + l16) * 4 + g) * 8 + e;
  WH[off] = h;
  WL[off] = f2bf(v - bf2f(h));
}

// ---------------------------------------------------------------------------
// cond_feat fp32 NCHW (131ch) -> chunked padded NHWC-32 hi/lo bf16:
// layout [b][cc(5)][194][194][32]. One block per (b, padded row, cc-chunk).
// ---------------------------------------------------------------------------
__global__ __launch_bounds__(256) void transpose_cond(const float* __restrict__ cond,
                                                      unsigned short* __restrict__ cH,
                                                      unsigned short* __restrict__ cL)
{
  const int tid = threadIdx.x;
  const int b  = blockIdx.x / PR_;
  const int yp = blockIdx.x % PR_;
  const int cc = blockIdx.y;
  const size_t ob = (((size_t)(b * 5 + cc) * PR_ + yp) * PR_) * 32;

  if (yp == 0 || yp == PR_ - 1) {                 // halo row: all zeros
    u32x4 z = {0, 0, 0, 0};
    for (int idx = tid; idx < PR_ * 4; idx += 256) {
      *(u32x4*)(cH + ob + (size_t)idx * 8) = z;
      *(u32x4*)(cL + ob + (size_t)idx * 8) = z;
    }
    return;
  }
  const int y = yp - 1;
  __shared__ float t[32][PR_];

  for (int idx = tid; idx < 32 * 192; idx += 256) {
    const int ci = idx / 192, px = idx % 192;
    const int c = cc * 32 + ci;
    t[ci][px + 1] = (c < 131) ? cond[(((size_t)b * 131 + c) * H_ + y) * W_ + px] : 0.f;
  }
  if (tid < 32) { t[tid][0] = 0.f; t[tid][PR_ - 1] = 0.f; }
  __syncthreads();
  for (int idx = tid; idx < PR_ * 4; idx += 256) {   // (px, 8ch-seg)
    const int px = idx >> 2, sg = idx & 3;
    u32x4 vh, vl;
    #pragma unroll
    for (int q = 0; q < 4; ++q) {
      const int c0 = sg * 8 + q * 2;
      const float va = t[c0][px], vb = t[c0 + 1][px];
      const unsigned short ha = f2bf(va), hb = f2bf(vb);
      vh[q] = (unsigned)ha | ((unsigned)hb << 16);
      const unsigned short la = f2bf(va - bf2f(ha)), lb = f2bf(vb - bf2f(hb));
      vl[q] = (unsigned)la | ((unsigned)lb << 16);
    }
    *(u32x4*)(cH + ob + (size_t)idx * 8) = vh;
    *(u32x4*)(cL + ob + (size_t)idx * 8) = vl;
  }
}

// ---------------------------------------------------------------------------
// zero halo of chunked padded NHWC-32 hi/lo pair ([b][2][194][194][32])
// ---------------------------------------------------------------------------
__global__ __launch_bounds__(256) void halo_zero(unsigned short* __restrict__ H,
                                                 unsigned short* __restrict__ L)
{
  const int idx = blockIdx.x * 256 + threadIdx.x;
  if (idx >= B_ * 2 * PR_ * PR_) return;
  const int r  = idx % (PR_ * PR_);
  const int yp = r / PR_, xp = r % PR_;
  if (yp == 0 || yp == PR_ - 1 || xp == 0 || xp == PR_ - 1) {
    u32x4 z = {0, 0, 0, 0};
    const size_t base = (size_t)idx * 32;
    #pragma unroll
    for (int j = 0; j < 4; ++j) {
      *(u32x4*)(H + base + j * 8) = z;
      *(u32x4*)(L + base + j * 8) = z;
    }
  }
}

// ---------------------------------------------------------------------------
// MFMA 3x3 conv, INPUT-STATIONARY K-loop (round-8 oc-strip wave split).
// Each staged B-fragment is read ONCE (center alignment) and consumed by all
// 3 kx taps into 3 shifted accumulator sets:
//   accP (kx=0, out=in+1), accC (kx=1, aligned), accM (kx=2, out=in-1).
// Boundary inputs (p0-1 -> out 0 via kx=0; p0+64 -> out 63 via kx=2) come from
// a lane-masked edge fragment accumulated into accC[0]/accC[3] (aligned).
// Epilogue: fp32 LDS buffer [64][76], 3 barrier-separated sum passes, then
// lrelu/split/store (EPI 0) or conv4 tanh/sigmoid epilogue (EPI 1).
// B ds_reads per (cc,ky) per wave: 12 (vs round-8's 24); MFMA 42 (vs 36).
// ---------------------------------------------------------------------------
template<int NCC, int NW, int EPI>
__global__ __launch_bounds__(NW * 64) void conv_mfma(
    const unsigned short* __restrict__ inH, const unsigned short* __restrict__ inL,
    const unsigned short* __restrict__ WH, const unsigned short* __restrict__ WL,
    const float* __restrict__ bias, const float* __restrict__ flow,
    unsigned short* __restrict__ outH, unsigned short* __restrict__ outL,
    float* __restrict__ om)
{
  const int tid = threadIdx.x;
  const int lane = tid & 63, wv = tid >> 6;
  const int g = lane >> 4, l16 = lane & 15;
  // XCD-chunked bijective remap (1152 blocks, 1152 % 8 == 0)
  const int nwg8 = (3 * 192 * B_) / 8;
  const int t = blockIdx.x;
  const int gi = (t & 7) * nwg8 + (t >> 3);
  const int p0 = (gi % 3) * 64;
  const int y  = (gi / 3) % 192;
  const int b  = gi / 576;

  // smem: staging 3 rows x (hi,lo) x 264 x 8 shorts = 25344B;
  // epilogue reuses it as float fbuf[64][76] = 19456B.
  __shared__ __align__(16) unsigned short smem[3 * 4224];

  f32x4 accC[4], accP[4], accM[4];
  {
    float bv[4];
    #pragma unroll
    for (int r = 0; r < 4; ++r) {
      const int oc = wv * 16 + g * 4 + r;
      bv[r] = (EPI == 1 && oc >= 27) ? 0.f : bias[oc];
    }
    #pragma unroll
    for (int n = 0; n < 4; ++n) {
      accC[n][0] = bv[0]; accC[n][1] = bv[1]; accC[n][2] = bv[2]; accC[n][3] = bv[3];
      accP[n][0] = 0.f; accP[n][1] = 0.f; accP[n][2] = 0.f; accP[n][3] = 0.f;
      accM[n][0] = 0.f; accM[n][1] = 0.f; accM[n][2] = 0.f; accM[n][3] = 0.f;
    }
  }

  const int fr = l16 * 4 + g;   // fragment-lane index (contiguous 16B slots)

  for (int cc = 0; cc < NCC; ++cc) {
    __syncthreads();
    // stage 3 rows x 66px x 32c hi/lo, swizzled: slot s holds cg = s ^ ((px>>1)&3)
    for (int ch = tid; ch < 792; ch += NW * 64) {
      const int row = ch / 264, c2 = ch % 264;
      const int px = c2 >> 2, s = c2 & 3;
      const int cg = s ^ ((px >> 1) & 3);
      const size_t so = ((((size_t)b * NCC + cc) * PR_ + (y + row)) * PR_ + p0 + px) * 32 + cg * 8;
      *(u32x4*)(smem + row * 4224 + c2 * 8)        = *(const u32x4*)(inH + so);
      *(u32x4*)(smem + row * 4224 + 2112 + c2 * 8) = *(const u32x4*)(inL + so);
    }
    __syncthreads();
    #pragma unroll
    for (int ky = 0; ky < 3; ++ky) {
      const unsigned short* stH = smem + ky * 4224;
      const unsigned short* stL = stH + 2112;
      // A fragments for all 3 kx (fragment-major, contiguous 1KB each)
      bf16x8 aH[3], aL[3];
      #pragma unroll
      for (int kx = 0; kx < 3; ++kx) {
        const int k = ky * 3 + kx;
        const size_t wo = ((((size_t)k * NW + wv) * NCC + cc) * 64 + fr) * 8;
        aH[kx] = *(const bf16x8*)(WH + wo);
        aL[kx] = *(const bf16x8*)(WL + wo);
      }
      // interior fragments: read once, feed 3 taps into shifted acc sets
      #pragma unroll
      for (int n = 0; n < 4; ++n) {
        const int pxt = n * 16 + l16 + 1;                 // staged center (input n*16+l16)
        const int bo = pxt * 32 + ((g ^ ((pxt >> 1) & 3)) * 8);
        const bf16x8 bH = *(const bf16x8*)(stH + bo);
        const bf16x8 bL = *(const bf16x8*)(stL + bo);
        accP[n] = __builtin_amdgcn_mfma_f32_16x16x32_bf16(aH[0], bH, accP[n], 0, 0, 0);
        accP[n] = __builtin_amdgcn_mfma_f32_16x16x32_bf16(aL[0], bH, accP[n], 0, 0, 0);
        accP[n] = __builtin_amdgcn_mfma_f32_16x16x32_bf16(aH[0], bL, accP[n], 0, 0, 0);
        accC[n] = __builtin_amdgcn_mfma_f32_16x16x32_bf16(aH[1], bH, accC[n], 0, 0, 0);
        accC[n] = __builtin_amdgcn_mfma_f32_16x16x32_bf16(aL[1], bH, accC[n], 0, 0, 0);
        accC[n] = __builtin_amdgcn_mfma_f32_16x16x32_bf16(aH[1], bL, accC[n], 0, 0, 0);
        accM[n] = __builtin_amdgcn_mfma_f32_16x16x32_bf16(aH[2], bH, accM[n], 0, 0, 0);
        accM[n] = __builtin_amdgcn_mfma_f32_16x16x32_bf16(aL[2], bH, accM[n], 0, 0, 0);
        accM[n] = __builtin_amdgcn_mfma_f32_16x16x32_bf16(aH[2], bL, accM[n], 0, 0, 0);
      }
      // boundary edge-fragment: lane 0 = staged 0 (input p0-1), lane 15 = staged 65
      {
        const bf16x8 z = {0, 0, 0, 0, 0, 0, 0, 0};
        // (0>>1)&3 = 0 and (65>>1)&3 = 0 -> slot = g for both
        bf16x8 xh0 = *(const bf16x8*)(stH + g * 8);
        bf16x8 xl0 = *(const bf16x8*)(stL + g * 8);
        xh0 = (l16 == 0) ? xh0 : z;  xl0 = (l16 == 0) ? xl0 : z;
        accC[0] = __builtin_amdgcn_mfma_f32_16x16x32_bf16(aH[0], xh0, accC[0], 0, 0, 0);
        accC[0] = __builtin_amdgcn_mfma_f32_16x16x32_bf16(aL[0], xh0, accC[0], 0, 0, 0);
        accC[0] = __builtin_amdgcn_mfma_f32_16x16x32_bf16(aH[0], xl0, accC[0], 0, 0, 0);
        bf16x8 xh1 = *(const bf16x8*)(stH + 65 * 32 + g * 8);
        bf16x8 xl1 = *(const bf16x8*)(stL + 65 * 32 + g * 8);
        xh1 = (l16 == 15) ? xh1 : z;  xl1 = (l16 == 15) ? xl1 : z;
        accC[3] = __builtin_amdgcn_mfma_f32_16x16x32_bf16(aH[2], xh1, accC[3], 0, 0, 0);
        accC[3] = __builtin_amdgcn_mfma_f32_16x16x32_bf16(aL[2], xh1, accC[3], 0, 0, 0);
        accC[3] = __builtin_amdgcn_mfma_f32_16x16x32_bf16(aH[2], xl1, accC[3], 0, 0, 0);
      }
    }
  }

  // ---- epilogue: sum shifted acc sets in fp32 LDS, then transform+store ----
  __syncthreads();
  float* fbuf = (float*)smem;                 // [64][76] floats
  const int cbase = wv * 16 + g * 4;
  #pragma unroll
  for (int n = 0; n < 4; ++n)
    *(f32x4*)(fbuf + (size_t)(n * 16 + l16) * 76 + cbase) = accC[n];
  __syncthreads();
  #pragma unroll
  for (int n = 0; n < 4; ++n) {
    const int o = n * 16 + l16 + 1;
    if (o < 64) {
      f32x4* p = (f32x4*)(fbuf + (size_t)o * 76 + cbase);
      f32x4 v = *p;
      v[0] += accP[n][0]; v[1] += accP[n][1]; v[2] += accP[n][2]; v[3] += accP[n][3];
      *p = v;
    }
  }
  __syncthreads();
  #pragma unroll
  for (int n = 0; n < 4; ++n) {
    const int o = n * 16 + l16 - 1;
    if (o >= 0) {
      f32x4* p = (f32x4*)(fbuf + (size_t)o * 76 + cbase);
      f32x4 v = *p;
      v[0] += accM[n][0]; v[1] += accM[n][1]; v[2] += accM[n][2]; v[3] += accM[n][3];
      *p = v;
    }
  }
  __syncthreads();

  if (EPI == 0) {
    // lrelu -> hi/lo split -> coalesced chunked store (256 threads: px x 16ch)
    const int px = tid >> 2, cq = tid & 3;
    const float* src = fbuf + (size_t)px * 76 + cq * 16;
    float w[16];
    #pragma unroll
    for (int i = 0; i < 4; ++i) {
      const f32x4 v = *(const f32x4*)(src + i * 4);
      #pragma unroll
      for (int r = 0; r < 4; ++r) {
        const float x = v[r];
        w[i * 4 + r] = (x >= 0.f) ? x : 0.1f * x;
      }
    }
    u32x4 H0, H1, L0, L1;
    #pragma unroll
    for (int j = 0; j < 4; ++j) {
      const float a0 = w[2 * j], b0 = w[2 * j + 1];
      const unsigned short ha = f2bf(a0), hb = f2bf(b0);
      H0[j] = (unsigned)ha | ((unsigned)hb << 16);
      const unsigned short la = f2bf(a0 - bf2f(ha)), lb = f2bf(b0 - bf2f(hb));
      L0[j] = (unsigned)la | ((unsigned)lb << 16);
      const float a1 = w[8 + 2 * j], b1 = w[9 + 2 * j];
      const unsigned short ha1 = f2bf(a1), hb1 = f2bf(b1);
      H1[j] = (unsigned)ha1 | ((unsigned)hb1 << 16);
      const unsigned short la1 = f2bf(a1 - bf2f(ha1)), lb1 = f2bf(b1 - bf2f(hb1));
      L1[j] = (unsigned)la1 | ((unsigned)lb1 << 16);
    }
    const size_t ob = ((((size_t)b * 2 + (cq >> 1)) * PR_ + (y + 1)) * PR_ + (p0 + px + 1)) * 32
                    + (cq & 1) * 16;
    *(u32x4*)(outH + ob)     = H0;
    *(u32x4*)(outH + ob + 8) = H1;
    *(u32x4*)(outL + ob)     = L0;
    *(u32x4*)(outL + ob + 8) = L1;
  } else {
    // conv4: offsets (10*tanh + flow_yx) / sigmoid mask -> fp32 NCHW om
    for (int px = tid; px < 64; px += NW * 64) {
      #pragma unroll 1
      for (int oc = 0; oc < 27; ++oc) {
        float v = fbuf[(size_t)px * 76 + oc];
        if (oc < 18) {
          const float f = flow[(((size_t)b * 2 + ((oc & 1) ? 0 : 1)) * H_ + y) * W_ + p0 + px];
          v = 10.f * tanhf(v) + f;
        } else {
          v = 1.f / (1.f + expf(-v));
        }
        om[((size_t)(b * 27 + oc) * HW_) + (size_t)y * W_ + p0 + px] = v;
      }
    }
  }
}

// ---------------------------------------------------------------------------
// deform weight (O=64,C=64,3,3) fp32 -> FRAGMENT-MAJOR bf16:
// W2F[k][o/16][c/32][l16][g][8] — contiguous 1KB per A-fragment.
// ---------------------------------------------------------------------------
__global__ __launch_bounds__(256) void prep_w2(const float* __restrict__ w,
                                               unsigned short* __restrict__ W2)
{
  const int i = blockIdx.x * 256 + threadIdx.x;
  if (i < 64 * 64 * 9) {
    const int o = i / 576;
    const int rem = i % 576;
    const int c = rem / 9;
    const int k = rem % 9;
    const int wv = o >> 4, l16 = o & 15;
    const int half = c >> 5, g = (c >> 3) & 3, e = c & 7;
    const size_t off = (((((size_t)k * 4 + wv) * 2 + half) * 16 + l16) * 4 + g) * 8 + e;
    W2[off] = f2bf(w[i]);
  }
}

// ---------------------------------------------------------------------------
// x NCHW fp32 -> NHWC bf16: xTb[b][p][c]
// ---------------------------------------------------------------------------
__global__ __launch_bounds__(256) void transpose_x(const float* __restrict__ x,
                                                   unsigned short* __restrict__ xTb)
{
  const int tid = threadIdx.x;
  const int lane = tid & 63, wv = tid >> 6;
  const int blocksPerB = HW_ / 64;
  const int b = blockIdx.x / blocksPerB;
  const int p0 = (blockIdx.x % blocksPerB) * 64;

  __shared__ float t[64][65];
  const float* xb = x + (size_t)b * C_ * HW_;
  #pragma unroll
  for (int j = 0; j < 16; ++j) {
    const int c = wv * 16 + j;
    t[c][lane] = xb[(size_t)c * HW_ + p0 + lane];
  }
  __syncthreads();
  unsigned short* xo = xTb + ((size_t)b * HW_ + p0) * 64;
  const int c4 = (tid & 15) * 4;
  const int pb = tid >> 4;
  #pragma unroll
  for (int pp = 0; pp < 4; ++pp) {
    const int p = pb + 16 * pp;
    ushort4 v = { f2bf(t[c4][p]), f2bf(t[c4+1][p]), f2bf(t[c4+2][p]), f2bf(t[c4+3][p]) };
    *(ushort4*)(xo + (size_t)p * 64 + c4) = v;
  }
}

// ---------------------------------------------------------------------------
// Deformable conv, bf16 MFMA (round-8 version, verified — unchanged)
// ---------------------------------------------------------------------------
__global__ __launch_bounds__(256) void deform_k(
    const unsigned short* __restrict__ xTb, const float* __restrict__ om,
    const unsigned short* __restrict__ W2, const float* __restrict__ bias,
    float* __restrict__ out)
{
  const int tid = threadIdx.x;
  const int lane = tid & 63, wv = tid >> 6;
  const int g = lane >> 4;
  const int l16 = lane & 15;
  const int blocksPerB = HW_ / 64;
  const int b = blockIdx.x / blocksPerB;
  const int rem = blockIdx.x % blocksPerB;
  const int h = (rem * 64) / W_;
  const int w0 = (rem * 64) % W_;

  __shared__ int   ci[4][9][64];
  __shared__ float cw[4][9][64];
  __shared__ __align__(16) unsigned short valk[64 * 64];

  for (int idx = tid; idx < 9 * 64; idx += 256) {
    const int k = idx >> 6, p = idx & 63;
    const size_t base = (size_t)b * 27 * HW_ + (size_t)h * W_ + w0 + p;
    const float dy = om[base + (size_t)(2 * k) * HW_];
    const float dx = om[base + (size_t)(2 * k + 1) * HW_];
    const float m  = om[base + (size_t)(18 + k) * HW_];
    const int ky = k / 3, kx = k - ky * 3;
    const float py = dy + (float)(h - 1 + ky);
    const float px = dx + (float)(w0 + p - 1 + kx);
    const float y0f = floorf(py), x0f = floorf(px);
    const float ly = py - y0f, lx = px - x0f;
    const int y0 = (int)y0f, x0 = (int)x0f;
    const int y1 = y0 + 1, x1 = x0 + 1;
    float w00 = (1.f - ly) * (1.f - lx), w01 = (1.f - ly) * lx;
    float w10 = ly * (1.f - lx),        w11 = ly * lx;
    if (!(y0 >= 0 && y0 < H_)) { w00 = 0.f; w01 = 0.f; }
    if (!(y1 >= 0 && y1 < H_)) { w10 = 0.f; w11 = 0.f; }
    if (!(x0 >= 0 && x0 < W_)) { w00 = 0.f; w10 = 0.f; }
    if (!(x1 >= 0 && x1 < W_)) { w01 = 0.f; w11 = 0.f; }
    const int yc0 = min(max(y0, 0), H_ - 1), yc1 = min(max(y1, 0), H_ - 1);
    const int xc0 = min(max(x0, 0), W_ - 1), xc1 = min(max(x1, 0), W_ - 1);
    ci[0][k][p] = yc0 * W_ + xc0;  cw[0][k][p] = m * w00;
    ci[1][k][p] = yc0 * W_ + xc1;  cw[1][k][p] = m * w01;
    ci[2][k][p] = yc1 * W_ + xc0;  cw[2][k][p] = m * w10;
    ci[3][k][p] = yc1 * W_ + xc1;  cw[3][k][p] = m * w11;
  }

  f32x4 acc[4];
  {
    float br[4];
    #pragma unroll
    for (int r = 0; r < 4; ++r) br[r] = bias[wv * 16 + g * 4 + r];
    #pragma unroll
    for (int n = 0; n < 4; ++n) { acc[n][0]=br[0]; acc[n][1]=br[1]; acc[n][2]=br[2]; acc[n][3]=br[3]; }
  }

  const unsigned short* xb = xTb + (size_t)b * HW_ * 64;
  const int fr = l16 * 4 + g;
  __syncthreads();

  for (int k = 0; k < 9; ++k) {
    #pragma unroll
    for (int i = 0; i < 2; ++i) {
      const int it = tid + (i << 8);
      const int cg = it & 7, p = it >> 3;
      const int i00 = ci[0][k][p], i01 = ci[1][k][p];
      const int i10 = ci[2][k][p], i11 = ci[3][k][p];
      const float q00 = cw[0][k][p], q01 = cw[1][k][p];
      const float q10 = cw[2][k][p], q11 = cw[3][k][p];
      const u32x4 va = *(const u32x4*)(xb + ((size_t)i00 * 64 + cg * 8));
      const u32x4 vb = *(const u32x4*)(xb + ((size_t)i01 * 64 + cg * 8));
      const u32x4 vc = *(const u32x4*)(xb + ((size_t)i10 * 64 + cg * 8));
      const u32x4 vd = *(const u32x4*)(xb + ((size_t)i11 * 64 + cg * 8));
      u32x4 res;
      #pragma unroll
      for (int j = 0; j < 4; ++j) {
        const float lo = q00*bflo(va[j]) + q01*bflo(vb[j]) + q10*bflo(vc[j]) + q11*bflo(vd[j]);
        const float hi = q00*bfhi(va[j]) + q01*bfhi(vb[j]) + q10*bfhi(vc[j]) + q11*bfhi(vd[j]);
        res[j] = pkbf(lo, hi);
      }
      *(u32x4*)&valk[(p << 6) + ((cg ^ (p & 7)) << 3)] = res;
    }

    const size_t wb = ((((size_t)k * 4 + wv) * 2) * 64 + fr) * 8;
    const bf16x8 a0 = *(const bf16x8*)(W2 + wb);
    const bf16x8 a1 = *(const bf16x8*)(W2 + wb + 512);

    __syncthreads();

    #pragma unroll
    for (int n = 0; n < 4; ++n) {
      const int p = n * 16 + l16;
      const bf16x8 b0 = *(const bf16x8*)&valk[(p << 6) + (((g    ) ^ (p & 7)) << 3)];
      const bf16x8 b1 = *(const bf16x8*)&valk[(p << 6) + (((g + 4) ^ (p & 7)) << 3)];
      acc[n] = __builtin_amdgcn_mfma_f32_16x16x32_bf16(a0, b0, acc[n], 0, 0, 0);
      acc[n] = __builtin_amdgcn_mfma_f32_16x16x32_bf16(a1, b1, acc[n], 0, 0, 0);
    }
    __syncthreads();
  }

  #pragma unroll
  for (int n = 0; n < 4; ++n) {
    #pragma unroll
    for (int r = 0; r < 4; ++r) {
      const int oc = wv * 16 + g * 4 + r;
      out[((size_t)(b * C_ + oc) * HW_) + (size_t)h * W_ + w0 + n * 16 + l16] = acc[n][r];
    }
  }
}

// ---------------------------------------------------------------------------
extern "C" void kernel_launch(void* const* d_in, const int* in_sizes, int n_in,
                              void* d_out, int out_size, void* d_ws, size_t ws_size,
                              hipStream_t stream) {
  const float* x         = (const float*)d_in[0];
  const float* cond_feat = (const float*)d_in[1];
  const float* flow      = (const float*)d_in[2];
  const float* w1 = (const float*)d_in[3];  const float* b1 = (const float*)d_in[4];
  const float* w2 = (const float*)d_in[5];  const float* b2 = (const float*)d_in[6];
  const float* w3 = (const float*)d_in[7];  const float* b3 = (const float*)d_in[8];
  const float* w4 = (const float*)d_in[9];  const float* b4 = (const float*)d_in[10];
  const float* wgt = (const float*)d_in[11]; const float* bias = (const float*)d_in[12];

  float* outp = (float*)d_out;

  // workspace layout (256B-aligned chunks)
  char* wsp = (char*)d_ws;
  size_t off = 0;
  auto alloc = [&](size_t bytes) { char* p = wsp + off; off += (bytes + 255) & ~(size_t)255; return p; };
  const size_t padHW = (size_t)PR_ * PR_;                       // 37636
  unsigned short* condH = (unsigned short*)alloc(B_ * 5 * padHW * 32 * 2);
  unsigned short* condL = (unsigned short*)alloc(B_ * 5 * padHW * 32 * 2);
  unsigned short* hA_H  = (unsigned short*)alloc(B_ * 2 * padHW * 32 * 2);
  unsigned short* hA_L  = (unsigned short*)alloc(B_ * 2 * padHW * 32 * 2);
  unsigned short* hB_H  = (unsigned short*)alloc(B_ * 2 * padHW * 32 * 2);
  unsigned short* hB_L  = (unsigned short*)alloc(B_ * 2 * padHW * 32 * 2);
  float*          om    = (float*)alloc((size_t)B_ * 27 * HW_ * 4);
  unsigned short* xTb   = (unsigned short*)alloc((size_t)B_ * HW_ * 64 * 2);
  unsigned short* W2d   = (unsigned short*)alloc(9 * 64 * 64 * 2);
  unsigned short* W1H   = (unsigned short*)alloc(9 * 64 * 160 * 2);
  unsigned short* W1L   = (unsigned short*)alloc(9 * 64 * 160 * 2);
  unsigned short* W2H   = (unsigned short*)alloc(9 * 64 * 64 * 2);
  unsigned short* W2L   = (unsigned short*)alloc(9 * 64 * 64 * 2);
  unsigned short* W3H   = (unsigned short*)alloc(9 * 64 * 64 * 2);
  unsigned short* W3L   = (unsigned short*)alloc(9 * 64 * 64 * 2);
  unsigned short* W4H   = (unsigned short*)alloc(9 * 32 * 64 * 2);
  unsigned short* W4L   = (unsigned short*)alloc(9 * 32 * 64 * 2);

  // weight prep (16x16 fragment-major)
  prep_cw<64, 131, 64, 160><<<(9*64*160 + 255)/256, 256, 0, stream>>>(w1, W1H, W1L);
  prep_cw<64, 64, 64, 64><<<(9*64*64 + 255)/256, 256, 0, stream>>>(w2, W2H, W2L);
  prep_cw<64, 64, 64, 64><<<(9*64*64 + 255)/256, 256, 0, stream>>>(w3, W3H, W3L);
  prep_cw<27, 64, 32, 64><<<(9*32*64 + 255)/256, 256, 0, stream>>>(w4, W4H, W4L);
  prep_w2<<<144, 256, 0, stream>>>(wgt, W2d);

  // input prep
  transpose_cond<<<dim3(B_ * PR_, 5), 256, 0, stream>>>(cond_feat, condH, condL);
  halo_zero<<<(B_ * 2 * PR_ * PR_ + 255)/256, 256, 0, stream>>>(hA_H, hA_L);
  halo_zero<<<(B_ * 2 * PR_ * PR_ + 255)/256, 256, 0, stream>>>(hB_H, hB_L);
  transpose_x<<<(B_ * HW_)/64, 256, 0, stream>>>(x, xTb);

  // conv chain (MFMA, input-stationary), 1D grid with XCD-chunked remap
  const int nwg = 3 * 192 * B_;   // 1152
  conv_mfma<5, 4, 0><<<nwg, 256, 0, stream>>>(condH, condL, W1H, W1L, b1, nullptr, hA_H, hA_L, nullptr);
  conv_mfma<2, 4, 0><<<nwg, 256, 0, stream>>>(hA_H, hA_L, W2H, W2L, b2, nullptr, hB_H, hB_L, nullptr);
  conv_mfma<2, 4, 0><<<nwg, 256, 0, stream>>>(hB_H, hB_L, W3H, W3L, b3, nullptr, hA_H, hA_L, nullptr);
  conv_mfma<2, 2, 1><<<nwg, 128, 0, stream>>>(hA_H, hA_L, W4H, W4L, b4, flow, nullptr, nullptr, om);

  // deformable conv
  deform_k<<<(B_ * HW_)/64, 256, 0, stream>>>(xTb, om, W2d, bias, outp);
}

// Round 13
// 176.770 us; speedup vs baseline: 1.5312x; 1.1774x over previous
//
#include <hip/hip_runtime.h>
#include <math.h>

#define B_ 2
#define C_ 64
#define H_ 192
#define W_ 192
#define HW_ (H_*W_)
#define PR_ 194      // padded row length (W+2)

typedef __attribute__((ext_vector_type(8))) short    bf16x8;
typedef __attribute__((ext_vector_type(4))) float    f32x4;
typedef __attribute__((ext_vector_type(4))) unsigned u32x4;

__device__ inline unsigned short f2bf(float f) {           // RNE fp32->bf16
  unsigned u = __float_as_uint(f);
  return (unsigned short)((u + 0x7fffu + ((u >> 16) & 1u)) >> 16);
}
__device__ inline float bf2f(unsigned short h) { return __uint_as_float((unsigned)h << 16); }
__device__ inline float bflo(unsigned u) { return __uint_as_float(u << 16); }
__device__ inline float bfhi(unsigned u) { return __uint_as_float(u & 0xffff0000u); }
__device__ inline unsigned pkbf(float a, float b) {
  unsigned ua = __float_as_uint(a), ub = __float_as_uint(b);
  ua = (ua + 0x7fffu + ((ua >> 16) & 1u)) >> 16;
  ub = (ub + 0x7fffu + ((ub >> 16) & 1u)) >> 16;
  return ua | (ub << 16);
}

// ---------------------------------------------------------------------------
// conv weight OIHW fp32 -> 16x16-FRAGMENT-MAJOR hi/lo bf16 (round-8 layout):
// WF[k][o/16][c/32][l16=o%16][g=(c%32)/8][8ch] — each MFMA A-fragment is one
// contiguous 1KB block (lane reads base + (l16*4+g)*16B, fully coalesced).
// ---------------------------------------------------------------------------
template<int O, int CIN, int OPAD, int CPAD>
__global__ __launch_bounds__(256) void prep_cw(const float* __restrict__ w,
                                               unsigned short* __restrict__ WH,
                                               unsigned short* __restrict__ WL)
{
  const int i = blockIdx.x * 256 + threadIdx.x;
  if (i >= 9 * OPAD * CPAD) return;
  const int k = i / (OPAD * CPAD);
  const int r = i % (OPAD * CPAD);
  const int o = r / CPAD;
  const int c = r % CPAD;
  float v = (o < O && c < CIN) ? w[((size_t)o * CIN + c) * 9 + k] : 0.f;
  const unsigned short h = f2bf(v);
  const int ot = o >> 4, l16 = o & 15;
  const int cc = c >> 5, g = (c >> 3) & 3, e = c & 7;
  const size_t off = (((((size_t)k * (OPAD / 16) + ot) * (CPAD / 32) + cc) * 16 + l16) * 4 + g) * 8 + e;
  WH[off] = h;
  WL[off] = f2bf(v - bf2f(h));
}

// ---------------------------------------------------------------------------
// cond_feat fp32 NCHW (131ch) -> chunked padded NHWC-32 hi/lo bf16:
// layout [b][cc(5)][194][194][32]. One block per (b, padded row, cc-chunk).
// ---------------------------------------------------------------------------
__global__ __launch_bounds__(256) void transpose_cond(const float* __restrict__ cond,
                                                      unsigned short* __restrict__ cH,
                                                      unsigned short* __restrict__ cL)
{
  const int tid = threadIdx.x;
  const int b  = blockIdx.x / PR_;
  const int yp = blockIdx.x % PR_;
  const int cc = blockIdx.y;
  const size_t ob = (((size_t)(b * 5 + cc) * PR_ + yp) * PR_) * 32;

  if (yp == 0 || yp == PR_ - 1) {                 // halo row: all zeros
    u32x4 z = {0, 0, 0, 0};
    for (int idx = tid; idx < PR_ * 4; idx += 256) {
      *(u32x4*)(cH + ob + (size_t)idx * 8) = z;
      *(u32x4*)(cL + ob + (size_t)idx * 8) = z;
    }
    return;
  }
  const int y = yp - 1;
  __shared__ float t[32][PR_];

  for (int idx = tid; idx < 32 * 192; idx += 256) {
    const int ci = idx / 192, px = idx % 192;
    const int c = cc * 32 + ci;
    t[ci][px + 1] = (c < 131) ? cond[(((size_t)b * 131 + c) * H_ + y) * W_ + px] : 0.f;
  }
  if (tid < 32) { t[tid][0] = 0.f; t[tid][PR_ - 1] = 0.f; }
  __syncthreads();
  for (int idx = tid; idx < PR_ * 4; idx += 256) {   // (px, 8ch-seg)
    const int px = idx >> 2, sg = idx & 3;
    u32x4 vh, vl;
    #pragma unroll
    for (int q = 0; q < 4; ++q) {
      const int c0 = sg * 8 + q * 2;
      const float va = t[c0][px], vb = t[c0 + 1][px];
      const unsigned short ha = f2bf(va), hb = f2bf(vb);
      vh[q] = (unsigned)ha | ((unsigned)hb << 16);
      const unsigned short la = f2bf(va - bf2f(ha)), lb = f2bf(vb - bf2f(hb));
      vl[q] = (unsigned)la | ((unsigned)lb << 16);
    }
    *(u32x4*)(cH + ob + (size_t)idx * 8) = vh;
    *(u32x4*)(cL + ob + (size_t)idx * 8) = vl;
  }
}

// ---------------------------------------------------------------------------
// zero halo of chunked padded NHWC-32 hi/lo pair ([b][2][194][194][32])
// ---------------------------------------------------------------------------
__global__ __launch_bounds__(256) void halo_zero(unsigned short* __restrict__ H,
                                                 unsigned short* __restrict__ L)
{
  const int idx = blockIdx.x * 256 + threadIdx.x;
  if (idx >= B_ * 2 * PR_ * PR_) return;
  const int r  = idx % (PR_ * PR_);
  const int yp = r / PR_, xp = r % PR_;
  if (yp == 0 || yp == PR_ - 1 || xp == 0 || xp == PR_ - 1) {
    u32x4 z = {0, 0, 0, 0};
    const size_t base = (size_t)idx * 32;
    #pragma unroll
    for (int j = 0; j < 4; ++j) {
      *(u32x4*)(H + base + j * 8) = z;
      *(u32x4*)(L + base + j * 8) = z;
    }
  }
}

// ---------------------------------------------------------------------------
// MFMA 3x3 conv (round-8, verified 46.5us conv1). Tile 64px x (NW*16) oc.
// oc-strip waves; weights fragment-major (coalesced 1KB A-loads).
// 3-term hi/lo MFMA: W_h*x_h + W_l*x_h + W_h*x_l.
// EPI 0: lrelu -> hi/lo split -> chunked padded store. EPI 1: conv4 epilogue.
// ---------------------------------------------------------------------------
template<int NCC, int NW, int EPI>
__global__ __launch_bounds__(NW * 64) void conv_mfma(
    const unsigned short* __restrict__ inH, const unsigned short* __restrict__ inL,
    const unsigned short* __restrict__ WH, const unsigned short* __restrict__ WL,
    const float* __restrict__ bias, const float* __restrict__ flow,
    unsigned short* __restrict__ outH, unsigned short* __restrict__ outL,
    float* __restrict__ om)
{
  constexpr int OPAD = NW * 16;
  const int tid = threadIdx.x;
  const int lane = tid & 63, wv = tid >> 6;
  const int g = lane >> 4, l16 = lane & 15;
  // XCD-chunked bijective remap (1152 blocks, 1152 % 8 == 0)
  const int nwg8 = (3 * 192 * B_) / 8;
  const int t = blockIdx.x;
  const int gi = (t & 7) * nwg8 + (t >> 3);
  const int p0 = (gi % 3) * 64;
  const int y  = (gi / 3) % 192;
  const int b  = gi / 576;

  // smem: staging 3 rows x (hi,lo) x 264 x 8 shorts = 25344B; epilogue reuses
  __shared__ __align__(16) unsigned short smem[3 * 4224];

  f32x4 acc[4];
  {
    float bv[4];
    #pragma unroll
    for (int r = 0; r < 4; ++r) {
      const int oc = wv * 16 + g * 4 + r;
      bv[r] = (EPI == 1 && oc >= 27) ? 0.f : bias[oc];
    }
    #pragma unroll
    for (int n = 0; n < 4; ++n) {
      acc[n][0] = bv[0]; acc[n][1] = bv[1]; acc[n][2] = bv[2]; acc[n][3] = bv[3];
    }
  }

  const int fr = l16 * 4 + g;   // fragment-lane index (contiguous 16B slots)

  for (int cc = 0; cc < NCC; ++cc) {
    __syncthreads();
    // stage 3 rows x 66px x 32c hi/lo, swizzled: slot s holds cg = s ^ ((px>>1)&3)
    for (int ch = tid; ch < 792; ch += NW * 64) {
      const int row = ch / 264, c2 = ch % 264;
      const int px = c2 >> 2, s = c2 & 3;
      const int cg = s ^ ((px >> 1) & 3);
      const size_t so = ((((size_t)b * NCC + cc) * PR_ + (y + row)) * PR_ + p0 + px) * 32 + cg * 8;
      *(u32x4*)(smem + row * 4224 + c2 * 8)        = *(const u32x4*)(inH + so);
      *(u32x4*)(smem + row * 4224 + 2112 + c2 * 8) = *(const u32x4*)(inL + so);
    }
    __syncthreads();
    #pragma unroll
    for (int ky = 0; ky < 3; ++ky) {
      const unsigned short* stH = smem + ky * 4224;
      const unsigned short* stL = stH + 2112;
      #pragma unroll
      for (int kx = 0; kx < 3; ++kx) {
        const int k = ky * 3 + kx;
        // fragment-major A: contiguous 1KB block per (k, wv, cc)
        const size_t wo = ((((size_t)k * NW + wv) * NCC + cc) * 64 + fr) * 8;
        const bf16x8 aH = *(const bf16x8*)(WH + wo);
        const bf16x8 aL = *(const bf16x8*)(WL + wo);
        #pragma unroll
        for (int n = 0; n < 4; ++n) {
          const int pxt = n * 16 + l16 + kx;
          const int bo = pxt * 32 + ((g ^ ((pxt >> 1) & 3)) * 8);
          const bf16x8 bH = *(const bf16x8*)(stH + bo);
          const bf16x8 bL = *(const bf16x8*)(stL + bo);
          acc[n] = __builtin_amdgcn_mfma_f32_16x16x32_bf16(aH, bH, acc[n], 0, 0, 0);
          acc[n] = __builtin_amdgcn_mfma_f32_16x16x32_bf16(aL, bH, acc[n], 0, 0, 0);
          acc[n] = __builtin_amdgcn_mfma_f32_16x16x32_bf16(aH, bL, acc[n], 0, 0, 0);
        }
      }
    }
  }

  if (EPI == 0) {
    // lrelu -> hi/lo split -> LDS transpose -> coalesced chunked store
    __syncthreads();
    unsigned short* eH = smem;
    unsigned short* eL = smem + 64 * 72;
    #pragma unroll
    for (int n = 0; n < 4; ++n) {
      const int px = n * 16 + l16;
      #pragma unroll
      for (int r = 0; r < 4; ++r) {
        const int c = wv * 16 + g * 4 + r;
        float v = acc[n][r];
        v = (v >= 0.f) ? v : 0.1f * v;
        const unsigned short h = f2bf(v);
        eH[px * 72 + c] = h;
        eL[px * 72 + c] = f2bf(v - bf2f(h));
      }
    }
    __syncthreads();
    const int px = tid >> 2, cq = tid & 3;
    const int cc2 = cq >> 1;
    const size_t ob = ((((size_t)b * 2 + cc2) * PR_ + (y + 1)) * PR_ + (p0 + px + 1)) * 32
                    + (cq & 1) * 16;
    *(u32x4*)(outH + ob)     = *(const u32x4*)(eH + px * 72 + cq * 16);
    *(u32x4*)(outH + ob + 8) = *(const u32x4*)(eH + px * 72 + cq * 16 + 8);
    *(u32x4*)(outL + ob)     = *(const u32x4*)(eL + px * 72 + cq * 16);
    *(u32x4*)(outL + ob + 8) = *(const u32x4*)(eL + px * 72 + cq * 16 + 8);
  } else {
    // conv4: offsets (10*tanh + flow_yx) / sigmoid mask -> fp32 NCHW om
    #pragma unroll
    for (int n = 0; n < 4; ++n) {
      const int px = p0 + n * 16 + l16;
      #pragma unroll
      for (int r = 0; r < 4; ++r) {
        const int oc = wv * 16 + g * 4 + r;
        if (oc >= 27) continue;
        float v = acc[n][r];
        if (oc < 18) {
          const float f = flow[(((size_t)b * 2 + ((oc & 1) ? 0 : 1)) * H_ + y) * W_ + px];
          v = 10.f * tanhf(v) + f;
        } else {
          v = 1.f / (1.f + expf(-v));
        }
        om[((size_t)(b * 27 + oc) * HW_) + (size_t)y * W_ + px] = v;
      }
    }
  }
}

// ---------------------------------------------------------------------------
// deform weight (O=64,C=64,3,3) fp32 -> FRAGMENT-MAJOR bf16:
// W2F[k][o/16][c/32][l16][g][8] — contiguous 1KB per A-fragment.
// ---------------------------------------------------------------------------
__global__ __launch_bounds__(256) void prep_w2(const float* __restrict__ w,
                                               unsigned short* __restrict__ W2)
{
  const int i = blockIdx.x * 256 + threadIdx.x;
  if (i < 64 * 64 * 9) {
    const int o = i / 576;
    const int rem = i % 576;
    const int c = rem / 9;
    const int k = rem % 9;
    const int wv = o >> 4, l16 = o & 15;
    const int half = c >> 5, g = (c >> 3) & 3, e = c & 7;
    const size_t off = (((((size_t)k * 4 + wv) * 2 + half) * 16 + l16) * 4 + g) * 8 + e;
    W2[off] = f2bf(w[i]);
  }
}

// ---------------------------------------------------------------------------
// x NCHW fp32 -> NHWC bf16: xTb[b][p][c]
// ---------------------------------------------------------------------------
__global__ __launch_bounds__(256) void transpose_x(const float* __restrict__ x,
                                                   unsigned short* __restrict__ xTb)
{
  const int tid = threadIdx.x;
  const int lane = tid & 63, wv = tid >> 6;
  const int blocksPerB = HW_ / 64;
  const int b = blockIdx.x / blocksPerB;
  const int p0 = (blockIdx.x % blocksPerB) * 64;

  __shared__ float t[64][65];
  const float* xb = x + (size_t)b * C_ * HW_;
  #pragma unroll
  for (int j = 0; j < 16; ++j) {
    const int c = wv * 16 + j;
    t[c][lane] = xb[(size_t)c * HW_ + p0 + lane];
  }
  __syncthreads();
  unsigned short* xo = xTb + ((size_t)b * HW_ + p0) * 64;
  const int c4 = (tid & 15) * 4;
  const int pb = tid >> 4;
  #pragma unroll
  for (int pp = 0; pp < 4; ++pp) {
    const int p = pb + 16 * pp;
    ushort4 v = { f2bf(t[c4][p]), f2bf(t[c4+1][p]), f2bf(t[c4+2][p]), f2bf(t[c4+3][p]) };
    *(ushort4*)(xo + (size_t)p * 64 + c4) = v;
  }
}

// ---------------------------------------------------------------------------
// Deformable conv, bf16 MFMA — round-8 math with DOUBLE-BUFFERED valk:
// gather(tap k+1) -> valk[(k+1)&1] issues BEFORE MFMA consumes valk[k&1];
// one barrier per tap (was 2) and gather latency hides under MFMA/ds_reads.
// XCD-chunked block remap: consecutive rows on one XCD -> x gathers L2-hit.
// ---------------------------------------------------------------------------
__global__ __launch_bounds__(256) void deform_k(
    const unsigned short* __restrict__ xTb, const float* __restrict__ om,
    const unsigned short* __restrict__ W2, const float* __restrict__ bias,
    float* __restrict__ out)
{
  const int tid = threadIdx.x;
  const int lane = tid & 63, wv = tid >> 6;
  const int g = lane >> 4;
  const int l16 = lane & 15;
  // XCD-chunked bijective remap (1152 blocks, 1152 % 8 == 0)
  const int blocksPerB = HW_ / 64;
  const int nwg8 = (B_ * blocksPerB) / 8;
  const int tt = blockIdx.x;
  const int gi = (tt & 7) * nwg8 + (tt >> 3);
  const int b = gi / blocksPerB;
  const int rem = gi % blocksPerB;
  const int h = (rem * 64) / W_;
  const int w0 = (rem * 64) % W_;

  __shared__ int   ci[4][9][64];
  __shared__ float cw[4][9][64];
  __shared__ __align__(16) unsigned short valk[2][64 * 64];

  for (int idx = tid; idx < 9 * 64; idx += 256) {
    const int k = idx >> 6, p = idx & 63;
    const size_t base = (size_t)b * 27 * HW_ + (size_t)h * W_ + w0 + p;
    const float dy = om[base + (size_t)(2 * k) * HW_];
    const float dx = om[base + (size_t)(2 * k + 1) * HW_];
    const float m  = om[base + (size_t)(18 + k) * HW_];
    const int ky = k / 3, kx = k - ky * 3;
    const float py = dy + (float)(h - 1 + ky);
    const float px = dx + (float)(w0 + p - 1 + kx);
    const float y0f = floorf(py), x0f = floorf(px);
    const float ly = py - y0f, lx = px - x0f;
    const int y0 = (int)y0f, x0 = (int)x0f;
    const int y1 = y0 + 1, x1 = x0 + 1;
    float w00 = (1.f - ly) * (1.f - lx), w01 = (1.f - ly) * lx;
    float w10 = ly * (1.f - lx),        w11 = ly * lx;
    if (!(y0 >= 0 && y0 < H_)) { w00 = 0.f; w01 = 0.f; }
    if (!(y1 >= 0 && y1 < H_)) { w10 = 0.f; w11 = 0.f; }
    if (!(x0 >= 0 && x0 < W_)) { w00 = 0.f; w10 = 0.f; }
    if (!(x1 >= 0 && x1 < W_)) { w01 = 0.f; w11 = 0.f; }
    const int yc0 = min(max(y0, 0), H_ - 1), yc1 = min(max(y1, 0), H_ - 1);
    const int xc0 = min(max(x0, 0), W_ - 1), xc1 = min(max(x1, 0), W_ - 1);
    ci[0][k][p] = yc0 * W_ + xc0;  cw[0][k][p] = m * w00;
    ci[1][k][p] = yc0 * W_ + xc1;  cw[1][k][p] = m * w01;
    ci[2][k][p] = yc1 * W_ + xc0;  cw[2][k][p] = m * w10;
    ci[3][k][p] = yc1 * W_ + xc1;  cw[3][k][p] = m * w11;
  }

  f32x4 acc[4];
  {
    float br[4];
    #pragma unroll
    for (int r = 0; r < 4; ++r) br[r] = bias[wv * 16 + g * 4 + r];
    #pragma unroll
    for (int n = 0; n < 4; ++n) { acc[n][0]=br[0]; acc[n][1]=br[1]; acc[n][2]=br[2]; acc[n][3]=br[3]; }
  }

  const unsigned short* xb = xTb + (size_t)b * HW_ * 64;
  const int fr = l16 * 4 + g;

  // gather helper: bilinear-sample tap k for this thread's 2 (p, cg) items
  auto GATHER = [&](int k, unsigned short* dst) {
    #pragma unroll
    for (int i = 0; i < 2; ++i) {
      const int it = tid + (i << 8);
      const int cg = it & 7, p = it >> 3;
      const int i00 = ci[0][k][p], i01 = ci[1][k][p];
      const int i10 = ci[2][k][p], i11 = ci[3][k][p];
      const float q00 = cw[0][k][p], q01 = cw[1][k][p];
      const float q10 = cw[2][k][p], q11 = cw[3][k][p];
      const u32x4 va = *(const u32x4*)(xb + ((size_t)i00 * 64 + cg * 8));
      const u32x4 vb = *(const u32x4*)(xb + ((size_t)i01 * 64 + cg * 8));
      const u32x4 vc = *(const u32x4*)(xb + ((size_t)i10 * 64 + cg * 8));
      const u32x4 vd = *(const u32x4*)(xb + ((size_t)i11 * 64 + cg * 8));
      u32x4 res;
      #pragma unroll
      for (int j = 0; j < 4; ++j) {
        const float lo = q00*bflo(va[j]) + q01*bflo(vb[j]) + q10*bflo(vc[j]) + q11*bflo(vd[j]);
        const float hi = q00*bfhi(va[j]) + q01*bfhi(vb[j]) + q10*bfhi(vc[j]) + q11*bfhi(vd[j]);
        res[j] = pkbf(lo, hi);
      }
      *(u32x4*)&dst[(p << 6) + ((cg ^ (p & 7)) << 3)] = res;
    }
  };

  __syncthreads();            // ci/cw ready
  GATHER(0, valk[0]);
  __syncthreads();            // valk[0] ready

  #pragma unroll
  for (int k = 0; k < 9; ++k) {
    if (k < 8) GATHER(k + 1, valk[(k + 1) & 1]);   // overlap with MFMA below

    const size_t wb = ((((size_t)k * 4 + wv) * 2) * 64 + fr) * 8;
    const bf16x8 a0 = *(const bf16x8*)(W2 + wb);
    const bf16x8 a1 = *(const bf16x8*)(W2 + wb + 512);

    const unsigned short* cbuf = valk[k & 1];
    #pragma unroll
    for (int n = 0; n < 4; ++n) {
      const int p = n * 16 + l16;
      const bf16x8 b0 = *(const bf16x8*)&cbuf[(p << 6) + (((g    ) ^ (p & 7)) << 3)];
      const bf16x8 b1 = *(const bf16x8*)&cbuf[(p << 6) + (((g + 4) ^ (p & 7)) << 3)];
      acc[n] = __builtin_amdgcn_mfma_f32_16x16x32_bf16(a0, b0, acc[n], 0, 0, 0);
      acc[n] = __builtin_amdgcn_mfma_f32_16x16x32_bf16(a1, b1, acc[n], 0, 0, 0);
    }
    __syncthreads();          // joins: gather(k+1) writes + MFMA(k) reads
  }

  #pragma unroll
  for (int n = 0; n < 4; ++n) {
    #pragma unroll
    for (int r = 0; r < 4; ++r) {
      const int oc = wv * 16 + g * 4 + r;
      out[((size_t)(b * C_ + oc) * HW_) + (size_t)h * W_ + w0 + n * 16 + l16] = acc[n][r];
    }
  }
}

// ---------------------------------------------------------------------------
extern "C" void kernel_launch(void* const* d_in, const int* in_sizes, int n_in,
                              void* d_out, int out_size, void* d_ws, size_t ws_size,
                              hipStream_t stream) {
  const float* x         = (const float*)d_in[0];
  const float* cond_feat = (const float*)d_in[1];
  const float* flow      = (const float*)d_in[2];
  const float* w1 = (const float*)d_in[3];  const float* b1 = (const float*)d_in[4];
  const float* w2 = (const float*)d_in[5];  const float* b2 = (const float*)d_in[6];
  const float* w3 = (const float*)d_in[7];  const float* b3 = (const float*)d_in[8];
  const float* w4 = (const float*)d_in[9];  const float* b4 = (const float*)d_in[10];
  const float* wgt = (const float*)d_in[11]; const float* bias = (const float*)d_in[12];

  float* outp = (float*)d_out;

  // workspace layout (256B-aligned chunks)
  char* wsp = (char*)d_ws;
  size_t off = 0;
  auto alloc = [&](size_t bytes) { char* p = wsp + off; off += (bytes + 255) & ~(size_t)255; return p; };
  const size_t padHW = (size_t)PR_ * PR_;                       // 37636
  unsigned short* condH = (unsigned short*)alloc(B_ * 5 * padHW * 32 * 2);
  unsigned short* condL = (unsigned short*)alloc(B_ * 5 * padHW * 32 * 2);
  unsigned short* hA_H  = (unsigned short*)alloc(B_ * 2 * padHW * 32 * 2);
  unsigned short* hA_L  = (unsigned short*)alloc(B_ * 2 * padHW * 32 * 2);
  unsigned short* hB_H  = (unsigned short*)alloc(B_ * 2 * padHW * 32 * 2);
  unsigned short* hB_L  = (unsigned short*)alloc(B_ * 2 * padHW * 32 * 2);
  float*          om    = (float*)alloc((size_t)B_ * 27 * HW_ * 4);
  unsigned short* xTb   = (unsigned short*)alloc((size_t)B_ * HW_ * 64 * 2);
  unsigned short* W2d   = (unsigned short*)alloc(9 * 64 * 64 * 2);
  unsigned short* W1H   = (unsigned short*)alloc(9 * 64 * 160 * 2);
  unsigned short* W1L   = (unsigned short*)alloc(9 * 64 * 160 * 2);
  unsigned short* W2H   = (unsigned short*)alloc(9 * 64 * 64 * 2);
  unsigned short* W2L   = (unsigned short*)alloc(9 * 64 * 64 * 2);
  unsigned short* W3H   = (unsigned short*)alloc(9 * 64 * 64 * 2);
  unsigned short* W3L   = (unsigned short*)alloc(9 * 64 * 64 * 2);
  unsigned short* W4H   = (unsigned short*)alloc(9 * 32 * 64 * 2);
  unsigned short* W4L   = (unsigned short*)alloc(9 * 32 * 64 * 2);

  // weight prep (16x16 fragment-major)
  prep_cw<64, 131, 64, 160><<<(9*64*160 + 255)/256, 256, 0, stream>>>(w1, W1H, W1L);
  prep_cw<64, 64, 64, 64><<<(9*64*64 + 255)/256, 256, 0, stream>>>(w2, W2H, W2L);
  prep_cw<64, 64, 64, 64><<<(9*64*64 + 255)/256, 256, 0, stream>>>(w3, W3H, W3L);
  prep_cw<27, 64, 32, 64><<<(9*32*64 + 255)/256, 256, 0, stream>>>(w4, W4H, W4L);
  prep_w2<<<144, 256, 0, stream>>>(wgt, W2d);

  // input prep
  transpose_cond<<<dim3(B_ * PR_, 5), 256, 0, stream>>>(cond_feat, condH, condL);
  halo_zero<<<(B_ * 2 * PR_ * PR_ + 255)/256, 256, 0, stream>>>(hA_H, hA_L);
  halo_zero<<<(B_ * 2 * PR_ * PR_ + 255)/256, 256, 0, stream>>>(hB_H, hB_L);
  transpose_x<<<(B_ * HW_)/64, 256, 0, stream>>>(x, xTb);

  // conv chain (MFMA, round-8 verified), 1D grid with XCD-chunked remap
  const int nwg = 3 * 192 * B_;   // 1152
  conv_mfma<5, 4, 0><<<nwg, 256, 0, stream>>>(condH, condL, W1H, W1L, b1, nullptr, hA_H, hA_L, nullptr);
  conv_mfma<2, 4, 0><<<nwg, 256, 0, stream>>>(hA_H, hA_L, W2H, W2L, b2, nullptr, hB_H, hB_L, nullptr);
  conv_mfma<2, 4, 0><<<nwg, 256, 0, stream>>>(hB_H, hB_L, W3H, W3L, b3, nullptr, hA_H, hA_L, nullptr);
  conv_mfma<2, 2, 1><<<nwg, 128, 0, stream>>>(hA_H, hA_L, W4H, W4L, b4, flow, nullptr, nullptr, om);

  // deformable conv (double-buffered)
  deform_k<<<(B_ * HW_)/64, 256, 0, stream>>>(xTb, om, W2d, bias, outp);
}

// Round 14
// 162.449 us; speedup vs baseline: 1.6662x; 1.0882x over previous
//
#include <hip/hip_runtime.h>
#include <math.h>

#define B_ 2
#define C_ 64
#define H_ 192
#define W_ 192
#define HW_ (H_*W_)
#define PR_ 194      // padded row length (W+2)

typedef __attribute__((ext_vector_type(8))) short    bf16x8;
typedef __attribute__((ext_vector_type(4))) float    f32x4;
typedef __attribute__((ext_vector_type(4))) unsigned u32x4;

__device__ inline unsigned short f2bf(float f) {           // RNE fp32->bf16
  unsigned u = __float_as_uint(f);
  return (unsigned short)((u + 0x7fffu + ((u >> 16) & 1u)) >> 16);
}
__device__ inline float bf2f(unsigned short h) { return __uint_as_float((unsigned)h << 16); }
__device__ inline float bflo(unsigned u) { return __uint_as_float(u << 16); }
__device__ inline float bfhi(unsigned u) { return __uint_as_float(u & 0xffff0000u); }
__device__ inline unsigned pkbf(float a, float b) {
  unsigned ua = __float_as_uint(a), ub = __float_as_uint(b);
  ua = (ua + 0x7fffu + ((ua >> 16) & 1u)) >> 16;
  ub = (ub + 0x7fffu + ((ub >> 16) & 1u)) >> 16;
  return ua | (ub << 16);
}

// ---------------------------------------------------------------------------
// conv weight OIHW fp32 -> 16x16-FRAGMENT-MAJOR hi/lo bf16:
// WF[k][o/16][c/32][l16=o%16][g=(c%32)/8][8ch] — 1KB contiguous per fragment.
// (device helper, called from prep_misc)
// ---------------------------------------------------------------------------
template<int O, int CIN, int OPAD, int CPAD>
__device__ inline void prep_cw_body(int i, const float* __restrict__ w,
                                    unsigned short* __restrict__ WH,
                                    unsigned short* __restrict__ WL)
{
  if (i >= 9 * OPAD * CPAD) return;
  const int k = i / (OPAD * CPAD);
  const int r = i % (OPAD * CPAD);
  const int o = r / CPAD;
  const int c = r % CPAD;
  float v = (o < O && c < CIN) ? w[((size_t)o * CIN + c) * 9 + k] : 0.f;
  const unsigned short h = f2bf(v);
  const int ot = o >> 4, l16 = o & 15;
  const int cc = c >> 5, g = (c >> 3) & 3, e = c & 7;
  const size_t off = (((((size_t)k * (OPAD / 16) + ot) * (CPAD / 32) + cc) * 16 + l16) * 4 + g) * 8 + e;
  WH[off] = h;
  WL[off] = f2bf(v - bf2f(h));
}

// ---------------------------------------------------------------------------
// Fused prep: [0,360) cw1 | [360,504) cw2 | [504,648) cw3 | [648,720) cw4 |
// [720,864) w2d | [864,2042) halo A/B | [2042,3194) transpose_x.
// ---------------------------------------------------------------------------
#define PM_CW1 360
#define PM_CW2 (PM_CW1 + 144)
#define PM_CW3 (PM_CW2 + 144)
#define PM_CW4 (PM_CW3 + 72)
#define PM_W2D (PM_CW4 + 144)
#define PM_HALO (PM_W2D + 1178)     // 2 * ceil(2*2*37636/256)=589 each
#define PM_TX  (PM_HALO + 1152)
__global__ __launch_bounds__(256) void prep_misc(
    const float* __restrict__ w1, const float* __restrict__ w2,
    const float* __restrict__ w3, const float* __restrict__ w4,
    const float* __restrict__ wgt, const float* __restrict__ x,
    unsigned short* __restrict__ W1H, unsigned short* __restrict__ W1L,
    unsigned short* __restrict__ W2H, unsigned short* __restrict__ W2L,
    unsigned short* __restrict__ W3H, unsigned short* __restrict__ W3L,
    unsigned short* __restrict__ W4H, unsigned short* __restrict__ W4L,
    unsigned short* __restrict__ W2d,
    unsigned short* __restrict__ hA_H, unsigned short* __restrict__ hA_L,
    unsigned short* __restrict__ hB_H, unsigned short* __restrict__ hB_L,
    unsigned short* __restrict__ xTb)
{
  const int bid = blockIdx.x;
  const int tid = threadIdx.x;

  if (bid < PM_CW1) {
    prep_cw_body<64, 131, 64, 160>(bid * 256 + tid, w1, W1H, W1L);
  } else if (bid < PM_CW2) {
    prep_cw_body<64, 64, 64, 64>((bid - PM_CW1) * 256 + tid, w2, W2H, W2L);
  } else if (bid < PM_CW3) {
    prep_cw_body<64, 64, 64, 64>((bid - PM_CW2) * 256 + tid, w3, W3H, W3L);
  } else if (bid < PM_CW4) {
    prep_cw_body<27, 64, 32, 64>((bid - PM_CW3) * 256 + tid, w4, W4H, W4L);
  } else if (bid < PM_W2D) {
    const int i = (bid - PM_CW4) * 256 + tid;
    if (i < 64 * 64 * 9) {
      const int o = i / 576;
      const int rem = i % 576;
      const int c = rem / 9;
      const int k = rem % 9;
      const int wv = o >> 4, l16 = o & 15;
      const int half = c >> 5, g = (c >> 3) & 3, e = c & 7;
      const size_t off = (((((size_t)k * 4 + wv) * 2 + half) * 16 + l16) * 4 + g) * 8 + e;
      W2d[off] = f2bf(wgt[i]);
    }
  } else if (bid < PM_HALO) {
    const int j = bid - PM_W2D;                  // 0..1177; 589 per buffer pair
    const int which = (j >= 589);
    unsigned short* H = which ? hB_H : hA_H;
    unsigned short* L = which ? hB_L : hA_L;
    const int idx = (j - which * 589) * 256 + tid;
    if (idx < B_ * 2 * PR_ * PR_) {
      const int r  = idx % (PR_ * PR_);
      const int yp = r / PR_, xp = r % PR_;
      if (yp == 0 || yp == PR_ - 1 || xp == 0 || xp == PR_ - 1) {
        u32x4 z = {0, 0, 0, 0};
        const size_t base = (size_t)idx * 32;
        #pragma unroll
        for (int q = 0; q < 4; ++q) {
          *(u32x4*)(H + base + q * 8) = z;
          *(u32x4*)(L + base + q * 8) = z;
        }
      }
    }
  } else {
    // transpose_x: x NCHW fp32 -> NHWC bf16 xTb[b][p][c]
    const int blk = bid - PM_HALO;               // 0..1151
    const int lane = tid & 63, wv = tid >> 6;
    const int blocksPerB = HW_ / 64;
    const int b = blk / blocksPerB;
    const int p0 = (blk % blocksPerB) * 64;
    __shared__ float t[64][65];
    const float* xb = x + (size_t)b * C_ * HW_;
    #pragma unroll
    for (int j = 0; j < 16; ++j) {
      const int c = wv * 16 + j;
      t[c][lane] = xb[(size_t)c * HW_ + p0 + lane];
    }
    __syncthreads();
    unsigned short* xo = xTb + ((size_t)b * HW_ + p0) * 64;
    const int c4 = (tid & 15) * 4;
    const int pb = tid >> 4;
    #pragma unroll
    for (int pp = 0; pp < 4; ++pp) {
      const int p = pb + 16 * pp;
      ushort4 v = { f2bf(t[c4][p]), f2bf(t[c4+1][p]), f2bf(t[c4+2][p]), f2bf(t[c4+3][p]) };
      *(ushort4*)(xo + (size_t)p * 64 + c4) = v;
    }
  }
}

// ---------------------------------------------------------------------------
// cond_feat fp32 NCHW (131ch) -> chunked padded NHWC-32 hi/lo bf16:
// layout [b][cc(5)][194][194][32]. One block per (b, padded row, cc-chunk).
// ---------------------------------------------------------------------------
__global__ __launch_bounds__(256) void transpose_cond(const float* __restrict__ cond,
                                                      unsigned short* __restrict__ cH,
                                                      unsigned short* __restrict__ cL)
{
  const int tid = threadIdx.x;
  const int b  = blockIdx.x / PR_;
  const int yp = blockIdx.x % PR_;
  const int cc = blockIdx.y;
  const size_t ob = (((size_t)(b * 5 + cc) * PR_ + yp) * PR_) * 32;

  if (yp == 0 || yp == PR_ - 1) {                 // halo row: all zeros
    u32x4 z = {0, 0, 0, 0};
    for (int idx = tid; idx < PR_ * 4; idx += 256) {
      *(u32x4*)(cH + ob + (size_t)idx * 8) = z;
      *(u32x4*)(cL + ob + (size_t)idx * 8) = z;
    }
    return;
  }
  const int y = yp - 1;
  __shared__ float t[32][PR_];

  for (int idx = tid; idx < 32 * 192; idx += 256) {
    const int ci = idx / 192, px = idx % 192;
    const int c = cc * 32 + ci;
    t[ci][px + 1] = (c < 131) ? cond[(((size_t)b * 131 + c) * H_ + y) * W_ + px] : 0.f;
  }
  if (tid < 32) { t[tid][0] = 0.f; t[tid][PR_ - 1] = 0.f; }
  __syncthreads();
  for (int idx = tid; idx < PR_ * 4; idx += 256) {   // (px, 8ch-seg)
    const int px = idx >> 2, sg = idx & 3;
    u32x4 vh, vl;
    #pragma unroll
    for (int q = 0; q < 4; ++q) {
      const int c0 = sg * 8 + q * 2;
      const float va = t[c0][px], vb = t[c0 + 1][px];
      const unsigned short ha = f2bf(va), hb = f2bf(vb);
      vh[q] = (unsigned)ha | ((unsigned)hb << 16);
      const unsigned short la = f2bf(va - bf2f(ha)), lb = f2bf(vb - bf2f(hb));
      vl[q] = (unsigned)la | ((unsigned)lb << 16);
    }
    *(u32x4*)(cH + ob + (size_t)idx * 8) = vh;
    *(u32x4*)(cL + ob + (size_t)idx * 8) = vl;
  }
}

// ---------------------------------------------------------------------------
// MFMA 3x3 conv (round-8, verified 46.5us conv1). Tile 64px x (NW*16) oc.
// oc-strip waves; weights fragment-major (coalesced 1KB A-loads).
// 3-term hi/lo MFMA: W_h*x_h + W_l*x_h + W_h*x_l.
// EPI 0: lrelu -> hi/lo split -> chunked padded store. EPI 1: conv4 epilogue.
// ---------------------------------------------------------------------------
template<int NCC, int NW, int EPI>
__global__ __launch_bounds__(NW * 64) void conv_mfma(
    const unsigned short* __restrict__ inH, const unsigned short* __restrict__ inL,
    const unsigned short* __restrict__ WH, const unsigned short* __restrict__ WL,
    const float* __restrict__ bias, const float* __restrict__ flow,
    unsigned short* __restrict__ outH, unsigned short* __restrict__ outL,
    float* __restrict__ om)
{
  constexpr int OPAD = NW * 16;
  const int tid = threadIdx.x;
  const int lane = tid & 63, wv = tid >> 6;
  const int g = lane >> 4, l16 = lane & 15;
  // XCD-chunked bijective remap (1152 blocks, 1152 % 8 == 0)
  const int nwg8 = (3 * 192 * B_) / 8;
  const int t = blockIdx.x;
  const int gi = (t & 7) * nwg8 + (t >> 3);
  const int p0 = (gi % 3) * 64;
  const int y  = (gi / 3) % 192;
  const int b  = gi / 576;

  // smem: staging 3 rows x (hi,lo) x 264 x 8 shorts = 25344B; epilogue reuses
  __shared__ __align__(16) unsigned short smem[3 * 4224];

  f32x4 acc[4];
  {
    float bv[4];
    #pragma unroll
    for (int r = 0; r < 4; ++r) {
      const int oc = wv * 16 + g * 4 + r;
      bv[r] = (EPI == 1 && oc >= 27) ? 0.f : bias[oc];
    }
    #pragma unroll
    for (int n = 0; n < 4; ++n) {
      acc[n][0] = bv[0]; acc[n][1] = bv[1]; acc[n][2] = bv[2]; acc[n][3] = bv[3];
    }
  }

  const int fr = l16 * 4 + g;   // fragment-lane index (contiguous 16B slots)

  for (int cc = 0; cc < NCC; ++cc) {
    __syncthreads();
    // stage 3 rows x 66px x 32c hi/lo, swizzled: slot s holds cg = s ^ ((px>>1)&3)
    for (int ch = tid; ch < 792; ch += NW * 64) {
      const int row = ch / 264, c2 = ch % 264;
      const int px = c2 >> 2, s = c2 & 3;
      const int cg = s ^ ((px >> 1) & 3);
      const size_t so = ((((size_t)b * NCC + cc) * PR_ + (y + row)) * PR_ + p0 + px) * 32 + cg * 8;
      *(u32x4*)(smem + row * 4224 + c2 * 8)        = *(const u32x4*)(inH + so);
      *(u32x4*)(smem + row * 4224 + 2112 + c2 * 8) = *(const u32x4*)(inL + so);
    }
    __syncthreads();
    #pragma unroll
    for (int ky = 0; ky < 3; ++ky) {
      const unsigned short* stH = smem + ky * 4224;
      const unsigned short* stL = stH + 2112;
      #pragma unroll
      for (int kx = 0; kx < 3; ++kx) {
        const int k = ky * 3 + kx;
        // fragment-major A: contiguous 1KB block per (k, wv, cc)
        const size_t wo = ((((size_t)k * NW + wv) * NCC + cc) * 64 + fr) * 8;
        const bf16x8 aH = *(const bf16x8*)(WH + wo);
        const bf16x8 aL = *(const bf16x8*)(WL + wo);
        #pragma unroll
        for (int n = 0; n < 4; ++n) {
          const int pxt = n * 16 + l16 + kx;
          const int bo = pxt * 32 + ((g ^ ((pxt >> 1) & 3)) * 8);
          const bf16x8 bH = *(const bf16x8*)(stH + bo);
          const bf16x8 bL = *(const bf16x8*)(stL + bo);
          acc[n] = __builtin_amdgcn_mfma_f32_16x16x32_bf16(aH, bH, acc[n], 0, 0, 0);
          acc[n] = __builtin_amdgcn_mfma_f32_16x16x32_bf16(aL, bH, acc[n], 0, 0, 0);
          acc[n] = __builtin_amdgcn_mfma_f32_16x16x32_bf16(aH, bL, acc[n], 0, 0, 0);
        }
      }
    }
  }

  if (EPI == 0) {
    // lrelu -> hi/lo split -> LDS transpose -> coalesced chunked store
    __syncthreads();
    unsigned short* eH = smem;
    unsigned short* eL = smem + 64 * 72;
    #pragma unroll
    for (int n = 0; n < 4; ++n) {
      const int px = n * 16 + l16;
      #pragma unroll
      for (int r = 0; r < 4; ++r) {
        const int c = wv * 16 + g * 4 + r;
        float v = acc[n][r];
        v = (v >= 0.f) ? v : 0.1f * v;
        const unsigned short h = f2bf(v);
        eH[px * 72 + c] = h;
        eL[px * 72 + c] = f2bf(v - bf2f(h));
      }
    }
    __syncthreads();
    const int px = tid >> 2, cq = tid & 3;
    const int cc2 = cq >> 1;
    const size_t ob = ((((size_t)b * 2 + cc2) * PR_ + (y + 1)) * PR_ + (p0 + px + 1)) * 32
                    + (cq & 1) * 16;
    *(u32x4*)(outH + ob)     = *(const u32x4*)(eH + px * 72 + cq * 16);
    *(u32x4*)(outH + ob + 8) = *(const u32x4*)(eH + px * 72 + cq * 16 + 8);
    *(u32x4*)(outL + ob)     = *(const u32x4*)(eL + px * 72 + cq * 16);
    *(u32x4*)(outL + ob + 8) = *(const u32x4*)(eL + px * 72 + cq * 16 + 8);
  } else {
    // conv4: offsets (10*tanh + flow_yx) / sigmoid mask -> fp32 NCHW om
    #pragma unroll
    for (int n = 0; n < 4; ++n) {
      const int px = p0 + n * 16 + l16;
      #pragma unroll
      for (int r = 0; r < 4; ++r) {
        const int oc = wv * 16 + g * 4 + r;
        if (oc >= 27) continue;
        float v = acc[n][r];
        if (oc < 18) {
          const float f = flow[(((size_t)b * 2 + ((oc & 1) ? 0 : 1)) * H_ + y) * W_ + px];
          v = 10.f * tanhf(v) + f;
        } else {
          v = 1.f / (1.f + expf(-v));
        }
        om[((size_t)(b * 27 + oc) * HW_) + (size_t)y * W_ + px] = v;
      }
    }
  }
}

// ---------------------------------------------------------------------------
// Deformable conv, bf16 MFMA — double-buffered valk (verified round 13):
// gather(tap k+1) -> valk[(k+1)&1] issues BEFORE MFMA consumes valk[k&1];
// one barrier per tap; gather latency hides under MFMA/ds_reads.
// XCD-chunked block remap: consecutive rows on one XCD -> x gathers L2-hit.
// ---------------------------------------------------------------------------
__global__ __launch_bounds__(256) void deform_k(
    const unsigned short* __restrict__ xTb, const float* __restrict__ om,
    const unsigned short* __restrict__ W2, const float* __restrict__ bias,
    float* __restrict__ out)
{
  const int tid = threadIdx.x;
  const int lane = tid & 63, wv = tid >> 6;
  const int g = lane >> 4;
  const int l16 = lane & 15;
  // XCD-chunked bijective remap (1152 blocks, 1152 % 8 == 0)
  const int blocksPerB = HW_ / 64;
  const int nwg8 = (B_ * blocksPerB) / 8;
  const int tt = blockIdx.x;
  const int gi = (tt & 7) * nwg8 + (tt >> 3);
  const int b = gi / blocksPerB;
  const int rem = gi % blocksPerB;
  const int h = (rem * 64) / W_;
  const int w0 = (rem * 64) % W_;

  __shared__ int   ci[4][9][64];
  __shared__ float cw[4][9][64];
  __shared__ __align__(16) unsigned short valk[2][64 * 64];

  for (int idx = tid; idx < 9 * 64; idx += 256) {
    const int k = idx >> 6, p = idx & 63;
    const size_t base = (size_t)b * 27 * HW_ + (size_t)h * W_ + w0 + p;
    const float dy = om[base + (size_t)(2 * k) * HW_];
    const float dx = om[base + (size_t)(2 * k + 1) * HW_];
    const float m  = om[base + (size_t)(18 + k) * HW_];
    const int ky = k / 3, kx = k - ky * 3;
    const float py = dy + (float)(h - 1 + ky);
    const float px = dx + (float)(w0 + p - 1 + kx);
    const float y0f = floorf(py), x0f = floorf(px);
    const float ly = py - y0f, lx = px - x0f;
    const int y0 = (int)y0f, x0 = (int)x0f;
    const int y1 = y0 + 1, x1 = x0 + 1;
    float w00 = (1.f - ly) * (1.f - lx), w01 = (1.f - ly) * lx;
    float w10 = ly * (1.f - lx),        w11 = ly * lx;
    if (!(y0 >= 0 && y0 < H_)) { w00 = 0.f; w01 = 0.f; }
    if (!(y1 >= 0 && y1 < H_)) { w10 = 0.f; w11 = 0.f; }
    if (!(x0 >= 0 && x0 < W_)) { w00 = 0.f; w10 = 0.f; }
    if (!(x1 >= 0 && x1 < W_)) { w01 = 0.f; w11 = 0.f; }
    const int yc0 = min(max(y0, 0), H_ - 1), yc1 = min(max(y1, 0), H_ - 1);
    const int xc0 = min(max(x0, 0), W_ - 1), xc1 = min(max(x1, 0), W_ - 1);
    ci[0][k][p] = yc0 * W_ + xc0;  cw[0][k][p] = m * w00;
    ci[1][k][p] = yc0 * W_ + xc1;  cw[1][k][p] = m * w01;
    ci[2][k][p] = yc1 * W_ + xc0;  cw[2][k][p] = m * w10;
    ci[3][k][p] = yc1 * W_ + xc1;  cw[3][k][p] = m * w11;
  }

  f32x4 acc[4];
  {
    float br[4];
    #pragma unroll
    for (int r = 0; r < 4; ++r) br[r] = bias[wv * 16 + g * 4 + r];
    #pragma unroll
    for (int n = 0; n < 4; ++n) { acc[n][0]=br[0]; acc[n][1]=br[1]; acc[n][2]=br[2]; acc[n][3]=br[3]; }
  }

  const unsigned short* xb = xTb + (size_t)b * HW_ * 64;
  const int fr = l16 * 4 + g;

  // gather helper: bilinear-sample tap k for this thread's 2 (p, cg) items
  auto GATHER = [&](int k, unsigned short* dst) {
    #pragma unroll
    for (int i = 0; i < 2; ++i) {
      const int it = tid + (i << 8);
      const int cg = it & 7, p = it >> 3;
      const int i00 = ci[0][k][p], i01 = ci[1][k][p];
      const int i10 = ci[2][k][p], i11 = ci[3][k][p];
      const float q00 = cw[0][k][p], q01 = cw[1][k][p];
      const float q10 = cw[2][k][p], q11 = cw[3][k][p];
      const u32x4 va = *(const u32x4*)(xb + ((size_t)i00 * 64 + cg * 8));
      const u32x4 vb = *(const u32x4*)(xb + ((size_t)i01 * 64 + cg * 8));
      const u32x4 vc = *(const u32x4*)(xb + ((size_t)i10 * 64 + cg * 8));
      const u32x4 vd = *(const u32x4*)(xb + ((size_t)i11 * 64 + cg * 8));
      u32x4 res;
      #pragma unroll
      for (int j = 0; j < 4; ++j) {
        const float lo = q00*bflo(va[j]) + q01*bflo(vb[j]) + q10*bflo(vc[j]) + q11*bflo(vd[j]);
        const float hi = q00*bfhi(va[j]) + q01*bfhi(vb[j]) + q10*bfhi(vc[j]) + q11*bfhi(vd[j]);
        res[j] = pkbf(lo, hi);
      }
      *(u32x4*)&dst[(p << 6) + ((cg ^ (p & 7)) << 3)] = res;
    }
  };

  __syncthreads();            // ci/cw ready
  GATHER(0, valk[0]);
  __syncthreads();            // valk[0] ready

  #pragma unroll
  for (int k = 0; k < 9; ++k) {
    if (k < 8) GATHER(k + 1, valk[(k + 1) & 1]);   // overlap with MFMA below

    const size_t wb = ((((size_t)k * 4 + wv) * 2) * 64 + fr) * 8;
    const bf16x8 a0 = *(const bf16x8*)(W2 + wb);
    const bf16x8 a1 = *(const bf16x8*)(W2 + wb + 512);

    const unsigned short* cbuf = valk[k & 1];
    #pragma unroll
    for (int n = 0; n < 4; ++n) {
      const int p = n * 16 + l16;
      const bf16x8 b0 = *(const bf16x8*)&cbuf[(p << 6) + (((g    ) ^ (p & 7)) << 3)];
      const bf16x8 b1 = *(const bf16x8*)&cbuf[(p << 6) + (((g + 4) ^ (p & 7)) << 3)];
      acc[n] = __builtin_amdgcn_mfma_f32_16x16x32_bf16(a0, b0, acc[n], 0, 0, 0);
      acc[n] = __builtin_amdgcn_mfma_f32_16x16x32_bf16(a1, b1, acc[n], 0, 0, 0);
    }
    __syncthreads();          // joins: gather(k+1) writes + MFMA(k) reads
  }

  #pragma unroll
  for (int n = 0; n < 4; ++n) {
    #pragma unroll
    for (int r = 0; r < 4; ++r) {
      const int oc = wv * 16 + g * 4 + r;
      out[((size_t)(b * C_ + oc) * HW_) + (size_t)h * W_ + w0 + n * 16 + l16] = acc[n][r];
    }
  }
}

// ---------------------------------------------------------------------------
extern "C" void kernel_launch(void* const* d_in, const int* in_sizes, int n_in,
                              void* d_out, int out_size, void* d_ws, size_t ws_size,
                              hipStream_t stream) {
  const float* x         = (const float*)d_in[0];
  const float* cond_feat = (const float*)d_in[1];
  const float* flow      = (const float*)d_in[2];
  const float* w1 = (const float*)d_in[3];  const float* b1 = (const float*)d_in[4];
  const float* w2 = (const float*)d_in[5];  const float* b2 = (const float*)d_in[6];
  const float* w3 = (const float*)d_in[7];  const float* b3 = (const float*)d_in[8];
  const float* w4 = (const float*)d_in[9];  const float* b4 = (const float*)d_in[10];
  const float* wgt = (const float*)d_in[11]; const float* bias = (const float*)d_in[12];

  float* outp = (float*)d_out;

  // workspace layout (256B-aligned chunks)
  char* wsp = (char*)d_ws;
  size_t off = 0;
  auto alloc = [&](size_t bytes) { char* p = wsp + off; off += (bytes + 255) & ~(size_t)255; return p; };
  const size_t padHW = (size_t)PR_ * PR_;                       // 37636
  unsigned short* condH = (unsigned short*)alloc(B_ * 5 * padHW * 32 * 2);
  unsigned short* condL = (unsigned short*)alloc(B_ * 5 * padHW * 32 * 2);
  unsigned short* hA_H  = (unsigned short*)alloc(B_ * 2 * padHW * 32 * 2);
  unsigned short* hA_L  = (unsigned short*)alloc(B_ * 2 * padHW * 32 * 2);
  unsigned short* hB_H  = (unsigned short*)alloc(B_ * 2 * padHW * 32 * 2);
  unsigned short* hB_L  = (unsigned short*)alloc(B_ * 2 * padHW * 32 * 2);
  float*          om    = (float*)alloc((size_t)B_ * 27 * HW_ * 4);
  unsigned short* xTb   = (unsigned short*)alloc((size_t)B_ * HW_ * 64 * 2);
  unsigned short* W2d   = (unsigned short*)alloc(9 * 64 * 64 * 2);
  unsigned short* W1H   = (unsigned short*)alloc(9 * 64 * 160 * 2);
  unsigned short* W1L   = (unsigned short*)alloc(9 * 64 * 160 * 2);
  unsigned short* W2H   = (unsigned short*)alloc(9 * 64 * 64 * 2);
  unsigned short* W2L   = (unsigned short*)alloc(9 * 64 * 64 * 2);
  unsigned short* W3H   = (unsigned short*)alloc(9 * 64 * 64 * 2);
  unsigned short* W3L   = (unsigned short*)alloc(9 * 64 * 64 * 2);
  unsigned short* W4H   = (unsigned short*)alloc(9 * 32 * 64 * 2);
  unsigned short* W4L   = (unsigned short*)alloc(9 * 32 * 64 * 2);

  // fused prep: all weight preps + halo zeros + transpose_x in ONE launch
  prep_misc<<<PM_TX, 256, 0, stream>>>(w1, w2, w3, w4, wgt, x,
                                       W1H, W1L, W2H, W2L, W3H, W3L, W4H, W4L,
                                       W2d, hA_H, hA_L, hB_H, hB_L, xTb);
  transpose_cond<<<dim3(B_ * PR_, 5), 256, 0, stream>>>(cond_feat, condH, condL);

  // conv chain (MFMA, round-8 verified), 1D grid with XCD-chunked remap
  const int nwg = 3 * 192 * B_;   // 1152
  conv_mfma<5, 4, 0><<<nwg, 256, 0, stream>>>(condH, condL, W1H, W1L, b1, nullptr, hA_H, hA_L, nullptr);
  conv_mfma<2, 4, 0><<<nwg, 256, 0, stream>>>(hA_H, hA_L, W2H, W2L, b2, nullptr, hB_H, hB_L, nullptr);
  conv_mfma<2, 4, 0><<<nwg, 256, 0, stream>>>(hB_H, hB_L, W3H, W3L, b3, nullptr, hA_H, hA_L, nullptr);
  conv_mfma<2, 2, 1><<<nwg, 128, 0, stream>>>(hA_H, hA_L, W4H, W4L, b4, flow, nullptr, nullptr, om);

  // deformable conv (double-buffered)
  deform_k<<<(B_ * HW_)/64, 256, 0, stream>>>(xTb, om, W2d, bias, outp);
}